// Round 1
// baseline (2164.433 us; speedup 1.0000x reference)
//
#include <hip/hip_runtime.h>
#include <hip/hip_bf16.h>
#include <stdint.h>

// LLaMA block on MI355X. All matmuls in bf16 MFMA (16x16x32), fp32 accumulate.
// Dims fixed: B=2, S=2048, D=2048, H=16, hd=128, FF=5632.

typedef __attribute__((ext_vector_type(8))) short bf16x8;     // 8 bf16 = 4 VGPR
typedef __attribute__((ext_vector_type(8))) unsigned short u16x8;
typedef __attribute__((ext_vector_type(4))) float f32x4;

__device__ __forceinline__ unsigned short f2bf(float f) {
  union { float f; unsigned int u; } c; c.f = f;
  unsigned int u = c.u + 0x7fffu + ((c.u >> 16) & 1u);   // RNE
  return (unsigned short)(u >> 16);
}
__device__ __forceinline__ float bf2f(unsigned short h) {
  union { unsigned int u; float f; } c; c.u = ((unsigned int)h) << 16;
  return c.f;
}

// ---------------------------------------------------------------------------
// RMSNorm: fp32 [rows][2048] -> bf16, y = x * rsqrt(mean(x^2)+eps) * g
// ---------------------------------------------------------------------------
__global__ __launch_bounds__(256)
void rmsnorm_bf16(const float* __restrict__ x, const float* __restrict__ g,
                  unsigned short* __restrict__ y)
{
  const long row = blockIdx.x;
  const float* xr = x + row * 2048;
  const int t = threadIdx.x;
  float4 a = *(const float4*)(xr + t * 8);
  float4 b = *(const float4*)(xr + t * 8 + 4);
  float ss = a.x*a.x + a.y*a.y + a.z*a.z + a.w*a.w
           + b.x*b.x + b.y*b.y + b.z*b.z + b.w*b.w;
#pragma unroll
  for (int off = 32; off >= 1; off >>= 1) ss += __shfl_xor(ss, off, 64);
  __shared__ float sm[4];
  if ((t & 63) == 0) sm[t >> 6] = ss;
  __syncthreads();
  float inv = rsqrtf((sm[0] + sm[1] + sm[2] + sm[3]) * (1.0f / 2048.0f) + 1e-6f);
  float4 ga = *(const float4*)(g + t * 8);
  float4 gb = *(const float4*)(g + t * 8 + 4);
  u16x8 ov;
  ov[0] = f2bf(a.x * inv * ga.x); ov[1] = f2bf(a.y * inv * ga.y);
  ov[2] = f2bf(a.z * inv * ga.z); ov[3] = f2bf(a.w * inv * ga.w);
  ov[4] = f2bf(b.x * inv * gb.x); ov[5] = f2bf(b.y * inv * gb.y);
  ov[6] = f2bf(b.z * inv * gb.z); ov[7] = f2bf(b.w * inv * gb.w);
  *(u16x8*)(y + row * 2048 + t * 8) = ov;
}

// ---------------------------------------------------------------------------
// Weight transpose + fp32->bf16: in [K][N] f32 -> out [N][K] bf16
// ---------------------------------------------------------------------------
__global__ __launch_bounds__(256)
void transpose_w(const float* __restrict__ in, unsigned short* __restrict__ outp,
                 int K, int N)
{
  __shared__ float tile[32][33];
  const int c0 = blockIdx.x * 32, r0 = blockIdx.y * 32;
  const int cx = threadIdx.x & 31, ry = threadIdx.x >> 5;
#pragma unroll
  for (int i = 0; i < 4; i++)
    tile[ry + i * 8][cx] = in[(long)(r0 + ry + i * 8) * N + c0 + cx];
  __syncthreads();
#pragma unroll
  for (int i = 0; i < 4; i++)
    outp[(long)(c0 + ry + i * 8) * K + r0 + cx] = f2bf(tile[cx][ry + i * 8]);
}

// ---------------------------------------------------------------------------
// GEMM: C[M,N] = A[M,K] * Bt[N,K]^T   (A,Bt bf16 row-major, fp32 accum)
// 128x128 tile, BK=64, 4 waves (each 64x64 = 4x4 16x16 frags), reg-staged LDS
// with XOR swizzle. EPI: 0=bf16 store, 1=silu->bf16, 2=mul(mulsrc)->bf16,
// 3=+res(fp32)->fp32.
// ---------------------------------------------------------------------------
template<int EPI>
__global__ __launch_bounds__(256)
void gemm_bt(const unsigned short* __restrict__ A,
             const unsigned short* __restrict__ Bt,
             void* __restrict__ Cout,
             const float* __restrict__ res,
             const unsigned short* __restrict__ mulsrc,
             int M, int N, int K)
{
  __shared__ unsigned short Alds[128 * 64];
  __shared__ unsigned short Blds[128 * 64];
  const int tid = threadIdx.x;
  const int lane = tid & 63, wave = tid >> 6;
  const int wr = wave >> 1, wc = wave & 1;
  const int l15 = lane & 15, lg = lane >> 4;
  const long m0 = (long)blockIdx.y * 128, n0 = (long)blockIdx.x * 128;

  f32x4 acc[4][4];
#pragma unroll
  for (int m = 0; m < 4; m++)
#pragma unroll
    for (int n = 0; n < 4; n++) acc[m][n] = f32x4{0.f, 0.f, 0.f, 0.f};

  const int row_s = tid >> 3;   // 0..31
  const int c8 = tid & 7;       // 16B chunk within 64-col row

  for (int kt = 0; kt < K; kt += 64) {
    uint4 ar[4], br[4];
#pragma unroll
    for (int i = 0; i < 4; i++) {
      int row = row_s + i * 32;
      ar[i] = *(const uint4*)(A + (m0 + row) * K + kt + c8 * 8);
      br[i] = *(const uint4*)(Bt + (n0 + row) * K + kt + c8 * 8);
    }
    __syncthreads();   // previous iter's LDS reads done
#pragma unroll
    for (int i = 0; i < 4; i++) {
      int row = row_s + i * 32;
      int off = (row * 128 + c8 * 16) ^ ((row & 7) << 4);
      *(uint4*)((char*)Alds + off) = ar[i];
      *(uint4*)((char*)Blds + off) = br[i];
    }
    __syncthreads();
#pragma unroll
    for (int kc = 0; kc < 2; kc++) {
      bf16x8 af[4], bfr[4];
#pragma unroll
      for (int m = 0; m < 4; m++) {
        int row = wr * 64 + m * 16 + l15;
        int off = (row * 128 + kc * 64 + lg * 16) ^ ((row & 7) << 4);
        af[m] = *(const bf16x8*)((const char*)Alds + off);
      }
#pragma unroll
      for (int n = 0; n < 4; n++) {
        int row = wc * 64 + n * 16 + l15;
        int off = (row * 128 + kc * 64 + lg * 16) ^ ((row & 7) << 4);
        bfr[n] = *(const bf16x8*)((const char*)Blds + off);
      }
#pragma unroll
      for (int m = 0; m < 4; m++)
#pragma unroll
        for (int n = 0; n < 4; n++)
          acc[m][n] = __builtin_amdgcn_mfma_f32_16x16x32_bf16(af[m], bfr[n], acc[m][n], 0, 0, 0);
    }
  }

#pragma unroll
  for (int m = 0; m < 4; m++)
#pragma unroll
    for (int n = 0; n < 4; n++)
#pragma unroll
      for (int r = 0; r < 4; r++) {
        long row = m0 + wr * 64 + m * 16 + lg * 4 + r;
        long col = n0 + wc * 64 + n * 16 + l15;
        float v = acc[m][n][r];
        if (EPI == 0) {
          ((unsigned short*)Cout)[row * N + col] = f2bf(v);
        } else if (EPI == 1) {
          float s = v / (1.f + __expf(-v));
          ((unsigned short*)Cout)[row * N + col] = f2bf(s);
        } else if (EPI == 2) {
          ((unsigned short*)Cout)[row * N + col] = f2bf(v * bf2f(mulsrc[row * N + col]));
        } else {
          ((float*)Cout)[row * N + col] = v + res[row * N + col];
        }
      }
}

// ---------------------------------------------------------------------------
// Causal flash attention. qkv bf16 [B*S][6144] (q|k|v, head-major within each).
// Block: (b,h, 64 q rows), 4 waves x 16 q rows. KV tiles of 64.
// ---------------------------------------------------------------------------
__global__ __launch_bounds__(256)
void attn_fwd(const unsigned short* __restrict__ qkv, unsigned short* __restrict__ out)
{
  __shared__ unsigned short Klds[64 * 128];   // [kv][d], swizzled (row&7)<<4
  __shared__ unsigned short Vt[128 * 64];     // [d][kv], swizzled ((d>>3)^d)&7<<4
  __shared__ unsigned short Plds[4][16 * 64]; // per-wave P, swizzled (q&7)<<4
  const int tid = threadIdx.x, lane = tid & 63, w = tid >> 6;
  const int l15 = lane & 15, lg = lane >> 4;
  const int qb = blockIdx.x * 64;
  const int b = blockIdx.y >> 4, hh = blockIdx.y & 15;
  const long rstride = 6144;
  const long base = (long)b * 2048 * 6144;
  const int qoff = hh * 128, koff = 2048 + hh * 128, voff = 4096 + hh * 128;

  bf16x8 qf[4];
  {
    long qrow = qb + w * 16 + l15;
#pragma unroll
    for (int kc = 0; kc < 4; kc++)
      qf[kc] = *(const bf16x8*)(qkv + base + qrow * rstride + qoff + kc * 32 + lg * 8);
  }
  f32x4 o[8];
#pragma unroll
  for (int dg = 0; dg < 8; dg++) o[dg] = f32x4{0.f, 0.f, 0.f, 0.f};
  float mrow[4] = {-1e30f, -1e30f, -1e30f, -1e30f};
  float lrow[4] = {0.f, 0.f, 0.f, 0.f};
  const float scale = 0.08838834764831845f;  // 1/sqrt(128)

  const int s_st = tid >> 4;        // 0..15
  const int d0 = (tid & 15) * 8;

  const int nt = blockIdx.x + 1;
  for (int t = 0; t < nt; t++) {
    const long kvb = base + (long)(t * 64) * rstride;
#pragma unroll
    for (int i = 0; i < 4; i++) {
      int srow = s_st + i * 16;
      uint4 kk = *(const uint4*)(qkv + kvb + (long)srow * rstride + koff + d0);
      *(uint4*)((char*)Klds + ((srow * 256 + d0 * 2) ^ ((srow & 7) << 4))) = kk;
      u16x8 vv = *(const u16x8*)(qkv + kvb + (long)srow * rstride + voff + d0);
#pragma unroll
      for (int j = 0; j < 8; j++) {
        int d = d0 + j;
        int xr = (((d >> 3) ^ d) & 7) << 4;
        *((unsigned short*)((char*)Vt + ((d * 128 + srow * 2) ^ xr))) = vv[j];
      }
    }
    __syncthreads();

    // S = Q K^T  -> lane holds S[q = lg*4+reg][kv = cg*16 + l15]
    f32x4 sacc[4];
#pragma unroll
    for (int cg = 0; cg < 4; cg++) {
      f32x4 a = f32x4{0.f, 0.f, 0.f, 0.f};
#pragma unroll
      for (int kc = 0; kc < 4; kc++) {
        int krow = cg * 16 + l15;
        bf16x8 kf = *(const bf16x8*)((char*)Klds +
                      ((krow * 256 + kc * 64 + lg * 16) ^ ((krow & 7) << 4)));
        a = __builtin_amdgcn_mfma_f32_16x16x32_bf16(qf[kc], kf, a, 0, 0, 0);
      }
      sacc[cg] = a;
    }

    // online softmax
    float p[4][4];
    float pm[4];
    const bool diag = (t == nt - 1);
#pragma unroll
    for (int r = 0; r < 4; r++) pm[r] = -1e30f;
#pragma unroll
    for (int cg = 0; cg < 4; cg++)
#pragma unroll
      for (int r = 0; r < 4; r++) {
        float v = sacc[cg][r] * scale;
        if (diag) {
          int kvg = t * 64 + cg * 16 + l15;
          int qg = qb + w * 16 + lg * 4 + r;
          if (kvg > qg) v = -1e30f;
        }
        p[cg][r] = v;
        pm[r] = fmaxf(pm[r], v);
      }
#pragma unroll
    for (int r = 0; r < 4; r++) {
#pragma unroll
      for (int off = 1; off < 16; off <<= 1)
        pm[r] = fmaxf(pm[r], __shfl_xor(pm[r], off, 64));
      float mn = fmaxf(mrow[r], pm[r]);
      float al = __expf(mrow[r] - mn);
      mrow[r] = mn;
      float s = 0.f;
#pragma unroll
      for (int cg = 0; cg < 4; cg++) { p[cg][r] = __expf(p[cg][r] - mn); s += p[cg][r]; }
#pragma unroll
      for (int off = 1; off < 16; off <<= 1)
        s += __shfl_xor(s, off, 64);
      lrow[r] = lrow[r] * al + s;
#pragma unroll
      for (int dg = 0; dg < 8; dg++) o[dg][r] *= al;
    }

    // P -> LDS (re-layout for PV a-operand)
#pragma unroll
    for (int cg = 0; cg < 4; cg++)
#pragma unroll
      for (int r = 0; r < 4; r++) {
        int q = lg * 4 + r;
        *((unsigned short*)((char*)&Plds[w][0] +
            ((q * 128 + (cg * 16 + l15) * 2) ^ ((q & 7) << 4)))) = f2bf(p[cg][r]);
      }
    asm volatile("s_waitcnt lgkmcnt(0)" ::: "memory");
    __builtin_amdgcn_sched_barrier(0);

    // O += P V
#pragma unroll
    for (int kc = 0; kc < 2; kc++) {
      bf16x8 pa = *(const bf16x8*)((char*)&Plds[w][0] +
                    ((l15 * 128 + kc * 64 + lg * 16) ^ ((l15 & 7) << 4)));
#pragma unroll
      for (int dg = 0; dg < 8; dg++) {
        int d = dg * 16 + l15;
        int xr = (((d >> 3) ^ d) & 7) << 4;
        bf16x8 vf = *(const bf16x8*)((char*)Vt + ((d * 128 + kc * 64 + lg * 16) ^ xr));
        o[dg] = __builtin_amdgcn_mfma_f32_16x16x32_bf16(pa, vf, o[dg], 0, 0, 0);
      }
    }
    __syncthreads();
  }

#pragma unroll
  for (int r = 0; r < 4; r++) {
    float inv = 1.f / lrow[r];
    long row = (long)b * 2048 + qb + w * 16 + lg * 4 + r;
#pragma unroll
    for (int dg = 0; dg < 8; dg++)
      out[row * 2048 + hh * 128 + dg * 16 + l15] = f2bf(o[dg][r] * inv);
  }
}

// ---------------------------------------------------------------------------
extern "C" void kernel_launch(void* const* d_in, const int* in_sizes, int n_in,
                              void* d_out, int out_size, void* d_ws, size_t ws_size,
                              hipStream_t stream)
{
  const float* x     = (const float*)d_in[0];
  const float* w_qkv = (const float*)d_in[1];
  const float* w_out = (const float*)d_in[2];
  const float* g1    = (const float*)d_in[3];
  const float* g2    = (const float*)d_in[4];
  const float* w1    = (const float*)d_in[5];
  const float* w3    = (const float*)d_in[6];
  const float* w2    = (const float*)d_in[7];
  float* outp = (float*)d_out;
  char* ws = (char*)d_ws;

  // workspace arena (bytes)
  unsigned short* wT  = (unsigned short*)(ws);                 // 25,165,824 (max 6144x2048 bf16)
  unsigned short* y   = (unsigned short*)(ws + 25165824);      // 16,777,216
  unsigned short* qkv = (unsigned short*)(ws + 41943040);      // 50,331,648
  unsigned short* att = (unsigned short*)(ws + 92274688);      // 16,777,216
  float*          x1  = (float*)(ws + 109051904);              // 33,554,432
  unsigned short* s1  = (unsigned short*)(ws + 142606336);     // 46,137,344 -> end 188,743,680
  unsigned short* h   = qkv;                                   // reuse (qkv dead after attn)

  // x1 = x + attn(rmsnorm(x,g1)) @ w_out
  rmsnorm_bf16<<<4096, 256, 0, stream>>>(x, g1, y);
  transpose_w<<<dim3(6144 / 32, 2048 / 32), 256, 0, stream>>>(w_qkv, wT, 2048, 6144);
  gemm_bt<0><<<dim3(48, 32), 256, 0, stream>>>(y, wT, qkv, nullptr, nullptr, 4096, 6144, 2048);
  attn_fwd<<<dim3(32, 32), 256, 0, stream>>>(qkv, att);
  transpose_w<<<dim3(64, 64), 256, 0, stream>>>(w_out, wT, 2048, 2048);
  gemm_bt<3><<<dim3(16, 32), 256, 0, stream>>>(att, wT, x1, x, nullptr, 4096, 2048, 2048);

  // out = x1 + swiglu(rmsnorm(x1,g2))
  rmsnorm_bf16<<<4096, 256, 0, stream>>>(x1, g2, y);
  transpose_w<<<dim3(176, 64), 256, 0, stream>>>(w1, wT, 2048, 5632);
  gemm_bt<1><<<dim3(44, 32), 256, 0, stream>>>(y, wT, s1, nullptr, nullptr, 4096, 5632, 2048);
  transpose_w<<<dim3(176, 64), 256, 0, stream>>>(w3, wT, 2048, 5632);
  gemm_bt<2><<<dim3(44, 32), 256, 0, stream>>>(y, wT, h, nullptr, s1, 4096, 5632, 2048);
  transpose_w<<<dim3(64, 176), 256, 0, stream>>>(w2, wT, 5632, 2048);
  gemm_bt<3><<<dim3(16, 32), 256, 0, stream>>>(h, wT, outp, x1, nullptr, 4096, 2048, 5632);
}

// Round 2
// 791.872 us; speedup vs baseline: 2.7333x; 2.7333x over previous
//
#include <hip/hip_runtime.h>
#include <hip/hip_bf16.h>
#include <stdint.h>

// LLaMA block on MI355X. All matmuls in bf16 MFMA (16x16x32), fp32 accumulate.
// Dims fixed: B=2, S=2048, D=2048, H=16, hd=128, FF=5632.

typedef __attribute__((ext_vector_type(8))) short bf16x8;     // 8 bf16 = 4 VGPR
typedef __attribute__((ext_vector_type(8))) unsigned short u16x8;
typedef __attribute__((ext_vector_type(4))) float f32x4;

__device__ __forceinline__ unsigned short f2bf(float f) {
  union { float f; unsigned int u; } c; c.f = f;
  unsigned int u = c.u + 0x7fffu + ((c.u >> 16) & 1u);   // RNE
  return (unsigned short)(u >> 16);
}
__device__ __forceinline__ float bf2f(unsigned short h) {
  union { unsigned int u; float f; } c; c.u = ((unsigned int)h) << 16;
  return c.f;
}

// async global->LDS, 16B per lane; LDS dest is wave-uniform base + lane*16
__device__ __forceinline__ void gload16(const void* g, void* l) {
  __builtin_amdgcn_global_load_lds(
      (const __attribute__((address_space(1))) void*)g,
      (__attribute__((address_space(3))) void*)l, 16, 0, 0);
}

// ---------------------------------------------------------------------------
// RMSNorm: fp32 [rows][2048] -> bf16, y = x * rsqrt(mean(x^2)+eps) * g
// ---------------------------------------------------------------------------
__global__ __launch_bounds__(256)
void rmsnorm_bf16(const float* __restrict__ x, const float* __restrict__ g,
                  unsigned short* __restrict__ y)
{
  const long row = blockIdx.x;
  const float* xr = x + row * 2048;
  const int t = threadIdx.x;
  float4 a = *(const float4*)(xr + t * 8);
  float4 b = *(const float4*)(xr + t * 8 + 4);
  float ss = a.x*a.x + a.y*a.y + a.z*a.z + a.w*a.w
           + b.x*b.x + b.y*b.y + b.z*b.z + b.w*b.w;
#pragma unroll
  for (int off = 32; off >= 1; off >>= 1) ss += __shfl_xor(ss, off, 64);
  __shared__ float sm[4];
  if ((t & 63) == 0) sm[t >> 6] = ss;
  __syncthreads();
  float inv = rsqrtf((sm[0] + sm[1] + sm[2] + sm[3]) * (1.0f / 2048.0f) + 1e-6f);
  float4 ga = *(const float4*)(g + t * 8);
  float4 gb = *(const float4*)(g + t * 8 + 4);
  u16x8 ov;
  ov[0] = f2bf(a.x * inv * ga.x); ov[1] = f2bf(a.y * inv * ga.y);
  ov[2] = f2bf(a.z * inv * ga.z); ov[3] = f2bf(a.w * inv * ga.w);
  ov[4] = f2bf(b.x * inv * gb.x); ov[5] = f2bf(b.y * inv * gb.y);
  ov[6] = f2bf(b.z * inv * gb.z); ov[7] = f2bf(b.w * inv * gb.w);
  *(u16x8*)(y + row * 2048 + t * 8) = ov;
}

// ---------------------------------------------------------------------------
// Weight transpose + fp32->bf16: in [K][N] f32 -> out [N][K] bf16
// ---------------------------------------------------------------------------
__global__ __launch_bounds__(256)
void transpose_w(const float* __restrict__ in, unsigned short* __restrict__ outp,
                 int K, int N)
{
  __shared__ float tile[32][33];
  const int c0 = blockIdx.x * 32, r0 = blockIdx.y * 32;
  const int cx = threadIdx.x & 31, ry = threadIdx.x >> 5;
#pragma unroll
  for (int i = 0; i < 4; i++)
    tile[ry + i * 8][cx] = in[(long)(r0 + ry + i * 8) * N + c0 + cx];
  __syncthreads();
#pragma unroll
  for (int i = 0; i < 4; i++)
    outp[(long)(c0 + ry + i * 8) * K + r0 + cx] = f2bf(tile[cx][ry + i * 8]);
}

// ---------------------------------------------------------------------------
// GEMM: C[M,N] = A[M,K] * Bt[N,K]^T   (A,Bt bf16 row-major, fp32 accum)
// m97 structure: 128x128 tile, BK=64, 4 waves, global_load_lds width=16
// staging (linear LDS dest + pre-swizzled global source), XOR-swizzled
// ds_read_b128 fragment reads, 2-barrier K-loop.
// EPI: 0=bf16 store, 1=silu->bf16, 2=mul(mulsrc)->bf16, 3=+res(fp32)->fp32.
// bf16 epilogues staged through LDS for 16B-coalesced stores.
// ---------------------------------------------------------------------------
template<int EPI>
__global__ __launch_bounds__(256)
void gemm_bt(const unsigned short* __restrict__ A,
             const unsigned short* __restrict__ Bt,
             void* __restrict__ Cout,
             const float* __restrict__ res,
             const unsigned short* __restrict__ mulsrc,
             int M, int N, int K)
{
  __shared__ unsigned short lds[2 * 128 * 64];   // A half [0,8192), B half [8192,16384) elems
  const int tid = threadIdx.x;
  const int lane = tid & 63, wave = tid >> 6;
  const int wr = wave >> 1, wc = wave & 1;
  const int l15 = lane & 15, lg = lane >> 4;
  const long m0 = (long)blockIdx.y * 128, n0 = (long)blockIdx.x * 128;

  f32x4 acc[4][4];
#pragma unroll
  for (int m = 0; m < 4; m++)
#pragma unroll
    for (int n = 0; n < 4; n++) acc[m][n] = f32x4{0.f, 0.f, 0.f, 0.f};

  // staging geometry: wave w, round i covers rows [w*32+i*8, +8), 64 cols bf16
  const int rsub = lane >> 3;           // 0..7: row within the 8-row stripe
  const int csw  = (lane & 7) ^ rsub;   // pre-swizzled source chunk (involution)
  const unsigned short* Ab = A  + (m0 + wave * 32 + rsub) * (long)K + csw * 8;
  const unsigned short* Bb = Bt + (n0 + wave * 32 + rsub) * (long)K + csw * 8;
  unsigned short* Al = lds + wave * 2048;          // 32 rows * 64 cols
  unsigned short* Bl = lds + 8192 + wave * 2048;

  for (int kt = 0; kt < K; kt += 64) {
    __syncthreads();   // previous iteration's LDS reads done before overwrite
#pragma unroll
    for (int i = 0; i < 4; i++) {
      gload16(Ab + (long)(i * 8) * K + kt, Al + i * 512);
      gload16(Bb + (long)(i * 8) * K + kt, Bl + i * 512);
    }
    __syncthreads();   // compiler drains vmcnt(0) here -> staged tile visible
#pragma unroll
    for (int kc = 0; kc < 2; kc++) {
      bf16x8 af[4], bfr[4];
#pragma unroll
      for (int m = 0; m < 4; m++) {
        int row = wr * 64 + m * 16 + l15;
        int off = row * 128 + ((kc * 64 + lg * 16) ^ ((row & 7) << 4));
        af[m] = *(const bf16x8*)((const char*)lds + off);
      }
#pragma unroll
      for (int n = 0; n < 4; n++) {
        int row = wc * 64 + n * 16 + l15;
        int off = 16384 + row * 128 + ((kc * 64 + lg * 16) ^ ((row & 7) << 4));
        bfr[n] = *(const bf16x8*)((const char*)lds + off);
      }
#pragma unroll
      for (int m = 0; m < 4; m++)
#pragma unroll
        for (int n = 0; n < 4; n++)
          acc[m][n] = __builtin_amdgcn_mfma_f32_16x16x32_bf16(af[m], bfr[n], acc[m][n], 0, 0, 0);
    }
  }

  if (EPI == 3) {
    // fp32 + residual: 16 lanes x 4B = 64B contiguous per segment, fine as-is
#pragma unroll
    for (int m = 0; m < 4; m++)
#pragma unroll
      for (int n = 0; n < 4; n++)
#pragma unroll
        for (int r = 0; r < 4; r++) {
          long row = m0 + wr * 64 + m * 16 + lg * 4 + r;
          long col = n0 + wc * 64 + n * 16 + l15;
          ((float*)Cout)[row * N + col] = acc[m][n][r] + res[row * N + col];
        }
    return;
  }

  // bf16 epilogues: stage C tile in (now dead) LDS, store coalesced 16B/lane
  __syncthreads();
  unsigned short* Cl = lds;   // viewed as [128][128] u16 = 32KB
#pragma unroll
  for (int m = 0; m < 4; m++)
#pragma unroll
    for (int n = 0; n < 4; n++)
#pragma unroll
      for (int r = 0; r < 4; r++) {
        float v = acc[m][n][r];
        if (EPI == 1) v = v / (1.f + __expf(-v));
        Cl[(wr * 64 + m * 16 + lg * 4 + r) * 128 + wc * 64 + n * 16 + l15] = f2bf(v);
      }
  __syncthreads();
#pragma unroll
  for (int r8 = 0; r8 < 8; r8++) {
    int id = tid + r8 * 256;            // 0..2047
    int row = id >> 4, c = (id & 15) * 8;
    long grow = m0 + row, gcol = n0 + c;
    u16x8 v = *(const u16x8*)(Cl + row * 128 + c);
    if (EPI == 2) {
      u16x8 mm = *(const u16x8*)(mulsrc + grow * N + gcol);
#pragma unroll
      for (int j = 0; j < 8; j++) v[j] = f2bf(bf2f(v[j]) * bf2f(mm[j]));
    }
    *(u16x8*)((unsigned short*)Cout + grow * N + gcol) = v;
  }
}

// ---------------------------------------------------------------------------
// Causal flash attention. qkv bf16 [B*S][6144] (q|k|v, head-major within each).
// Block: (b,h, 64 q rows), 4 waves x 16 q rows. KV tiles of 64.
// ---------------------------------------------------------------------------
__global__ __launch_bounds__(256)
void attn_fwd(const unsigned short* __restrict__ qkv, unsigned short* __restrict__ out)
{
  __shared__ unsigned short Klds[64 * 128];   // [kv][d], swizzled (row&7)<<4
  __shared__ unsigned short Vt[128 * 64];     // [d][kv], swizzled ((d>>3)^d)&7<<4
  __shared__ unsigned short Plds[4][16 * 64]; // per-wave P, swizzled (q&7)<<4
  const int tid = threadIdx.x, lane = tid & 63, w = tid >> 6;
  const int l15 = lane & 15, lg = lane >> 4;
  const int qb = blockIdx.x * 64;
  const int b = blockIdx.y >> 4, hh = blockIdx.y & 15;
  const long rstride = 6144;
  const long base = (long)b * 2048 * 6144;
  const int qoff = hh * 128, koff = 2048 + hh * 128, voff = 4096 + hh * 128;

  bf16x8 qf[4];
  {
    long qrow = qb + w * 16 + l15;
#pragma unroll
    for (int kc = 0; kc < 4; kc++)
      qf[kc] = *(const bf16x8*)(qkv + base + qrow * rstride + qoff + kc * 32 + lg * 8);
  }
  f32x4 o[8];
#pragma unroll
  for (int dg = 0; dg < 8; dg++) o[dg] = f32x4{0.f, 0.f, 0.f, 0.f};
  float mrow[4] = {-1e30f, -1e30f, -1e30f, -1e30f};
  float lrow[4] = {0.f, 0.f, 0.f, 0.f};
  const float scale = 0.08838834764831845f;  // 1/sqrt(128)

  const int s_st = tid >> 4;        // 0..15
  const int d0 = (tid & 15) * 8;

  const int nt = blockIdx.x + 1;
  for (int t = 0; t < nt; t++) {
    const long kvb = base + (long)(t * 64) * rstride;
#pragma unroll
    for (int i = 0; i < 4; i++) {
      int srow = s_st + i * 16;
      uint4 kk = *(const uint4*)(qkv + kvb + (long)srow * rstride + koff + d0);
      *(uint4*)((char*)Klds + ((srow * 256 + d0 * 2) ^ ((srow & 7) << 4))) = kk;
      u16x8 vv = *(const u16x8*)(qkv + kvb + (long)srow * rstride + voff + d0);
#pragma unroll
      for (int j = 0; j < 8; j++) {
        int d = d0 + j;
        int xr = (((d >> 3) ^ d) & 7) << 4;
        *((unsigned short*)((char*)Vt + ((d * 128 + srow * 2) ^ xr))) = vv[j];
      }
    }
    __syncthreads();

    // S = Q K^T  -> lane holds S[q = lg*4+reg][kv = cg*16 + l15]
    f32x4 sacc[4];
#pragma unroll
    for (int cg = 0; cg < 4; cg++) {
      f32x4 a = f32x4{0.f, 0.f, 0.f, 0.f};
#pragma unroll
      for (int kc = 0; kc < 4; kc++) {
        int krow = cg * 16 + l15;
        bf16x8 kf = *(const bf16x8*)((char*)Klds +
                      ((krow * 256 + kc * 64 + lg * 16) ^ ((krow & 7) << 4)));
        a = __builtin_amdgcn_mfma_f32_16x16x32_bf16(qf[kc], kf, a, 0, 0, 0);
      }
      sacc[cg] = a;
    }

    // online softmax
    float p[4][4];
    float pm[4];
    const bool diag = (t == nt - 1);
#pragma unroll
    for (int r = 0; r < 4; r++) pm[r] = -1e30f;
#pragma unroll
    for (int cg = 0; cg < 4; cg++)
#pragma unroll
      for (int r = 0; r < 4; r++) {
        float v = sacc[cg][r] * scale;
        if (diag) {
          int kvg = t * 64 + cg * 16 + l15;
          int qg = qb + w * 16 + lg * 4 + r;
          if (kvg > qg) v = -1e30f;
        }
        p[cg][r] = v;
        pm[r] = fmaxf(pm[r], v);
      }
#pragma unroll
    for (int r = 0; r < 4; r++) {
#pragma unroll
      for (int off = 1; off < 16; off <<= 1)
        pm[r] = fmaxf(pm[r], __shfl_xor(pm[r], off, 64));
      float mn = fmaxf(mrow[r], pm[r]);
      float al = __expf(mrow[r] - mn);
      mrow[r] = mn;
      float s = 0.f;
#pragma unroll
      for (int cg = 0; cg < 4; cg++) { p[cg][r] = __expf(p[cg][r] - mn); s += p[cg][r]; }
#pragma unroll
      for (int off = 1; off < 16; off <<= 1)
        s += __shfl_xor(s, off, 64);
      lrow[r] = lrow[r] * al + s;
#pragma unroll
      for (int dg = 0; dg < 8; dg++) o[dg][r] *= al;
    }

    // P -> LDS (re-layout for PV a-operand)
#pragma unroll
    for (int cg = 0; cg < 4; cg++)
#pragma unroll
      for (int r = 0; r < 4; r++) {
        int q = lg * 4 + r;
        *((unsigned short*)((char*)&Plds[w][0] +
            ((q * 128 + (cg * 16 + l15) * 2) ^ ((q & 7) << 4)))) = f2bf(p[cg][r]);
      }
    asm volatile("s_waitcnt lgkmcnt(0)" ::: "memory");
    __builtin_amdgcn_sched_barrier(0);

    // O += P V
#pragma unroll
    for (int kc = 0; kc < 2; kc++) {
      bf16x8 pa = *(const bf16x8*)((char*)&Plds[w][0] +
                    ((l15 * 128 + kc * 64 + lg * 16) ^ ((l15 & 7) << 4)));
#pragma unroll
      for (int dg = 0; dg < 8; dg++) {
        int d = dg * 16 + l15;
        int xr = (((d >> 3) ^ d) & 7) << 4;
        bf16x8 vf = *(const bf16x8*)((char*)Vt + ((d * 128 + kc * 64 + lg * 16) ^ xr));
        o[dg] = __builtin_amdgcn_mfma_f32_16x16x32_bf16(pa, vf, o[dg], 0, 0, 0);
      }
    }
    __syncthreads();
  }

#pragma unroll
  for (int r = 0; r < 4; r++) {
    float inv = 1.f / lrow[r];
    long row = (long)b * 2048 + qb + w * 16 + lg * 4 + r;
#pragma unroll
    for (int dg = 0; dg < 8; dg++)
      out[row * 2048 + hh * 128 + dg * 16 + l15] = f2bf(o[dg][r] * inv);
  }
}

// ---------------------------------------------------------------------------
extern "C" void kernel_launch(void* const* d_in, const int* in_sizes, int n_in,
                              void* d_out, int out_size, void* d_ws, size_t ws_size,
                              hipStream_t stream)
{
  const float* x     = (const float*)d_in[0];
  const float* w_qkv = (const float*)d_in[1];
  const float* w_out = (const float*)d_in[2];
  const float* g1    = (const float*)d_in[3];
  const float* g2    = (const float*)d_in[4];
  const float* w1    = (const float*)d_in[5];
  const float* w3    = (const float*)d_in[6];
  const float* w2    = (const float*)d_in[7];
  float* outp = (float*)d_out;
  char* ws = (char*)d_ws;

  // workspace arena (bytes)
  unsigned short* wT  = (unsigned short*)(ws);                 // 25,165,824 (max 6144x2048 bf16)
  unsigned short* y   = (unsigned short*)(ws + 25165824);      // 16,777,216
  unsigned short* qkv = (unsigned short*)(ws + 41943040);      // 50,331,648
  unsigned short* att = (unsigned short*)(ws + 92274688);      // 16,777,216
  float*          x1  = (float*)(ws + 109051904);              // 33,554,432
  unsigned short* s1  = (unsigned short*)(ws + 142606336);     // 46,137,344 -> end 188,743,680
  unsigned short* h   = qkv;                                   // reuse (qkv dead after attn)

  // x1 = x + attn(rmsnorm(x,g1)) @ w_out
  rmsnorm_bf16<<<4096, 256, 0, stream>>>(x, g1, y);
  transpose_w<<<dim3(6144 / 32, 2048 / 32), 256, 0, stream>>>(w_qkv, wT, 2048, 6144);
  gemm_bt<0><<<dim3(48, 32), 256, 0, stream>>>(y, wT, qkv, nullptr, nullptr, 4096, 6144, 2048);
  attn_fwd<<<dim3(32, 32), 256, 0, stream>>>(qkv, att);
  transpose_w<<<dim3(64, 64), 256, 0, stream>>>(w_out, wT, 2048, 2048);
  gemm_bt<3><<<dim3(16, 32), 256, 0, stream>>>(att, wT, x1, x, nullptr, 4096, 2048, 2048);

  // out = x1 + swiglu(rmsnorm(x1,g2))
  rmsnorm_bf16<<<4096, 256, 0, stream>>>(x1, g2, y);
  transpose_w<<<dim3(176, 64), 256, 0, stream>>>(w1, wT, 2048, 5632);
  gemm_bt<1><<<dim3(44, 32), 256, 0, stream>>>(y, wT, s1, nullptr, nullptr, 4096, 5632, 2048);
  transpose_w<<<dim3(176, 64), 256, 0, stream>>>(w3, wT, 2048, 5632);
  gemm_bt<2><<<dim3(44, 32), 256, 0, stream>>>(y, wT, h, nullptr, s1, 4096, 5632, 2048);
  transpose_w<<<dim3(64, 176), 256, 0, stream>>>(w2, wT, 5632, 2048);
  gemm_bt<3><<<dim3(16, 32), 256, 0, stream>>>(h, wT, outp, x1, nullptr, 4096, 2048, 5632);
}

// Round 3
// 716.506 us; speedup vs baseline: 3.0208x; 1.1052x over previous
//
#include <hip/hip_runtime.h>
#include <hip/hip_bf16.h>
#include <stdint.h>

// LLaMA block on MI355X. All matmuls in bf16 MFMA (16x16x32), fp32 accumulate.
// Dims fixed: B=2, S=2048, D=2048, H=16, hd=128, FF=5632.

typedef __attribute__((ext_vector_type(8))) short bf16x8;     // 8 bf16 = 4 VGPR
typedef __attribute__((ext_vector_type(8))) unsigned short u16x8;
typedef __attribute__((ext_vector_type(4))) float f32x4;

__device__ __forceinline__ unsigned short f2bf(float f) {
  union { float f; unsigned int u; } c; c.f = f;
  unsigned int u = c.u + 0x7fffu + ((c.u >> 16) & 1u);   // RNE
  return (unsigned short)(u >> 16);
}
__device__ __forceinline__ float bf2f(unsigned short h) {
  union { unsigned int u; float f; } c; c.u = ((unsigned int)h) << 16;
  return c.f;
}

// async global->LDS, 16B per lane; LDS dest is wave-uniform base + lane*16
__device__ __forceinline__ void gload16(const void* g, void* l) {
  __builtin_amdgcn_global_load_lds(
      (const __attribute__((address_space(1))) void*)g,
      (__attribute__((address_space(3))) void*)l, 16, 0, 0);
}

// ---------------------------------------------------------------------------
// RMSNorm: fp32 [rows][2048] -> bf16, y = x * rsqrt(mean(x^2)+eps) * g
// ---------------------------------------------------------------------------
__global__ __launch_bounds__(256)
void rmsnorm_bf16(const float* __restrict__ x, const float* __restrict__ g,
                  unsigned short* __restrict__ y)
{
  const long row = blockIdx.x;
  const float* xr = x + row * 2048;
  const int t = threadIdx.x;
  float4 a = *(const float4*)(xr + t * 8);
  float4 b = *(const float4*)(xr + t * 8 + 4);
  float ss = a.x*a.x + a.y*a.y + a.z*a.z + a.w*a.w
           + b.x*b.x + b.y*b.y + b.z*b.z + b.w*b.w;
#pragma unroll
  for (int off = 32; off >= 1; off >>= 1) ss += __shfl_xor(ss, off, 64);
  __shared__ float sm[4];
  if ((t & 63) == 0) sm[t >> 6] = ss;
  __syncthreads();
  float inv = rsqrtf((sm[0] + sm[1] + sm[2] + sm[3]) * (1.0f / 2048.0f) + 1e-6f);
  float4 ga = *(const float4*)(g + t * 8);
  float4 gb = *(const float4*)(g + t * 8 + 4);
  u16x8 ov;
  ov[0] = f2bf(a.x * inv * ga.x); ov[1] = f2bf(a.y * inv * ga.y);
  ov[2] = f2bf(a.z * inv * ga.z); ov[3] = f2bf(a.w * inv * ga.w);
  ov[4] = f2bf(b.x * inv * gb.x); ov[5] = f2bf(b.y * inv * gb.y);
  ov[6] = f2bf(b.z * inv * gb.z); ov[7] = f2bf(b.w * inv * gb.w);
  *(u16x8*)(y + row * 2048 + t * 8) = ov;
}

// ---------------------------------------------------------------------------
// Weight transpose + fp32->bf16: in [K][N] f32 -> out [N][K] bf16
// ---------------------------------------------------------------------------
__global__ __launch_bounds__(256)
void transpose_w(const float* __restrict__ in, unsigned short* __restrict__ outp,
                 int K, int N)
{
  __shared__ float tile[32][33];
  const int c0 = blockIdx.x * 32, r0 = blockIdx.y * 32;
  const int cx = threadIdx.x & 31, ry = threadIdx.x >> 5;
#pragma unroll
  for (int i = 0; i < 4; i++)
    tile[ry + i * 8][cx] = in[(long)(r0 + ry + i * 8) * N + c0 + cx];
  __syncthreads();
#pragma unroll
  for (int i = 0; i < 4; i++)
    outp[(long)(c0 + ry + i * 8) * K + r0 + cx] = f2bf(tile[cx][ry + i * 8]);
}

// ---------------------------------------------------------------------------
// V transpose: qkv V-section [b][s][h][d] -> vT [b][h][d][s]   (bf16)
// ---------------------------------------------------------------------------
__global__ __launch_bounds__(256)
void transpose_v(const unsigned short* __restrict__ qkv, unsigned short* __restrict__ vT)
{
  __shared__ unsigned short tile[32][34];   // +2 pad
  const int bh = blockIdx.z, b = bh >> 4, hh = bh & 15;
  const int s0 = blockIdx.x * 32, d0 = blockIdx.y * 32;
  const int cx = threadIdx.x & 31, ry = threadIdx.x >> 5;
  const unsigned short* src = qkv + (long)b * 2048 * 6144 + 4096 + hh * 128;
#pragma unroll
  for (int i = 0; i < 4; i++)
    tile[ry + i * 8][cx] = src[(long)(s0 + ry + i * 8) * 6144 + d0 + cx];
  __syncthreads();
  unsigned short* o = vT + ((long)bh * 128 + d0) * 2048 + s0;
#pragma unroll
  for (int i = 0; i < 4; i++)
    o[(long)(ry + i * 8) * 2048 + cx] = tile[cx][ry + i * 8];
}

// ---------------------------------------------------------------------------
// GEMM: C[M,N] = A[M,K] * Bt[N,K]^T   (A,Bt bf16 row-major, fp32 accum)
// m97 structure: 128x128 tile, BK=64, 4 waves, global_load_lds width=16
// staging (linear LDS dest + pre-swizzled global source), XOR-swizzled
// ds_read_b128 fragment reads, 2-barrier K-loop, XCD-swizzled blockIdx.
// EPI: 0=bf16 store, 1=silu->bf16, 2=mul(mulsrc)->bf16, 3=+res(fp32)->fp32.
// ---------------------------------------------------------------------------
template<int EPI>
__global__ __launch_bounds__(256)
void gemm_bt(const unsigned short* __restrict__ A,
             const unsigned short* __restrict__ Bt,
             void* __restrict__ Cout,
             const float* __restrict__ res,
             const unsigned short* __restrict__ mulsrc,
             int M, int N, int K)
{
  __shared__ unsigned short lds[2 * 128 * 64];   // A half [0,8192), B half [8192,16384)
  const int tid = threadIdx.x;
  const int lane = tid & 63, wave = tid >> 6;
  const int wr = wave >> 1, wc = wave & 1;
  const int l15 = lane & 15, lg = lane >> 4;

  // XCD-aware swizzle (all grids here have nwg % 8 == 0)
  const int nwg = gridDim.x * gridDim.y;
  int wg = blockIdx.y * gridDim.x + blockIdx.x;
  wg = (wg & 7) * (nwg >> 3) + (wg >> 3);
  const int bx = wg % gridDim.x, by = wg / gridDim.x;
  const long m0 = (long)by * 128, n0 = (long)bx * 128;

  f32x4 acc[4][4];
#pragma unroll
  for (int m = 0; m < 4; m++)
#pragma unroll
    for (int n = 0; n < 4; n++) acc[m][n] = f32x4{0.f, 0.f, 0.f, 0.f};

  // staging geometry: wave w, round i covers rows [w*32+i*8, +8), 64 cols bf16
  const int rsub = lane >> 3;           // 0..7: row within the 8-row stripe
  const int csw  = (lane & 7) ^ rsub;   // pre-swizzled source chunk (involution)
  const unsigned short* Ab = A  + (m0 + wave * 32 + rsub) * (long)K + csw * 8;
  const unsigned short* Bb = Bt + (n0 + wave * 32 + rsub) * (long)K + csw * 8;
  unsigned short* Al = lds + wave * 2048;          // 32 rows * 64 cols
  unsigned short* Bl = lds + 8192 + wave * 2048;

  for (int kt = 0; kt < K; kt += 64) {
    __syncthreads();   // previous iteration's LDS reads done before overwrite
#pragma unroll
    for (int i = 0; i < 4; i++) {
      gload16(Ab + (long)(i * 8) * K + kt, Al + i * 512);
      gload16(Bb + (long)(i * 8) * K + kt, Bl + i * 512);
    }
    __syncthreads();   // compiler drains vmcnt(0) here -> staged tile visible
#pragma unroll
    for (int kc = 0; kc < 2; kc++) {
      bf16x8 af[4], bfr[4];
#pragma unroll
      for (int m = 0; m < 4; m++) {
        int row = wr * 64 + m * 16 + l15;
        int off = row * 128 + ((kc * 64 + lg * 16) ^ ((row & 7) << 4));
        af[m] = *(const bf16x8*)((const char*)lds + off);
      }
#pragma unroll
      for (int n = 0; n < 4; n++) {
        int row = wc * 64 + n * 16 + l15;
        int off = 16384 + row * 128 + ((kc * 64 + lg * 16) ^ ((row & 7) << 4));
        bfr[n] = *(const bf16x8*)((const char*)lds + off);
      }
#pragma unroll
      for (int m = 0; m < 4; m++)
#pragma unroll
        for (int n = 0; n < 4; n++)
          acc[m][n] = __builtin_amdgcn_mfma_f32_16x16x32_bf16(af[m], bfr[n], acc[m][n], 0, 0, 0);
    }
  }

  if (EPI == 3) {
#pragma unroll
    for (int m = 0; m < 4; m++)
#pragma unroll
      for (int n = 0; n < 4; n++)
#pragma unroll
        for (int r = 0; r < 4; r++) {
          long row = m0 + wr * 64 + m * 16 + lg * 4 + r;
          long col = n0 + wc * 64 + n * 16 + l15;
          ((float*)Cout)[row * N + col] = acc[m][n][r] + res[row * N + col];
        }
    return;
  }

  // bf16 epilogues: stage C tile in (now dead) LDS, store coalesced 16B/lane
  __syncthreads();
  unsigned short* Cl = lds;   // viewed as [128][128] u16 = 32KB
#pragma unroll
  for (int m = 0; m < 4; m++)
#pragma unroll
    for (int n = 0; n < 4; n++)
#pragma unroll
      for (int r = 0; r < 4; r++) {
        float v = acc[m][n][r];
        if (EPI == 1) v = v / (1.f + __expf(-v));
        Cl[(wr * 64 + m * 16 + lg * 4 + r) * 128 + wc * 64 + n * 16 + l15] = f2bf(v);
      }
  __syncthreads();
#pragma unroll
  for (int r8 = 0; r8 < 8; r8++) {
    int id = tid + r8 * 256;            // 0..2047
    int row = id >> 4, c = (id & 15) * 8;
    long grow = m0 + row, gcol = n0 + c;
    u16x8 v = *(const u16x8*)(Cl + row * 128 + c);
    if (EPI == 2) {
      u16x8 mm = *(const u16x8*)(mulsrc + grow * N + gcol);
#pragma unroll
      for (int j = 0; j < 8; j++) v[j] = f2bf(bf2f(v[j]) * bf2f(mm[j]));
    }
    *(u16x8*)((unsigned short*)Cout + grow * N + gcol) = v;
  }
}

// ---------------------------------------------------------------------------
// Causal flash attention, paired q-tiles for load balance.
// Block (ip, bh): q-tiles A=ip and B=31-ip (64 rows each), 4 waves x 16 q rows.
// KV tiles of 64 staged once, used by both q-tiles. V pre-transposed (vT).
// ---------------------------------------------------------------------------
#define QSTEP(qf, mrow, lrow, o, qb, isdiag) do {                              \
    f32x4 sacc[4];                                                             \
    __builtin_amdgcn_s_setprio(1);                                             \
    _Pragma("unroll")                                                          \
    for (int cg = 0; cg < 4; cg++) {                                           \
      f32x4 a = f32x4{0.f, 0.f, 0.f, 0.f};                                     \
      _Pragma("unroll")                                                        \
      for (int kc = 0; kc < 4; kc++) {                                         \
        int krow = cg * 16 + l15;                                              \
        bf16x8 kf = *(const bf16x8*)((char*)Klds +                             \
            (krow * 256 + ((kc * 64 + lg * 16) ^ ((krow & 7) << 4))));         \
        a = __builtin_amdgcn_mfma_f32_16x16x32_bf16(qf[kc], kf, a, 0, 0, 0);   \
      }                                                                        \
      sacc[cg] = a;                                                            \
    }                                                                          \
    __builtin_amdgcn_s_setprio(0);                                             \
    float p[4][4], pm[4];                                                      \
    _Pragma("unroll")                                                          \
    for (int r = 0; r < 4; r++) pm[r] = -1e30f;                                \
    _Pragma("unroll")                                                          \
    for (int cg = 0; cg < 4; cg++)                                             \
      _Pragma("unroll")                                                        \
      for (int r = 0; r < 4; r++) {                                            \
        float v = sacc[cg][r] * scale;                                         \
        if (isdiag) {                                                          \
          int kvg = kv0 + cg * 16 + l15;                                       \
          int qg = qb + w * 16 + lg * 4 + r;                                   \
          if (kvg > qg) v = -1e30f;                                            \
        }                                                                      \
        p[cg][r] = v;                                                          \
        pm[r] = fmaxf(pm[r], v);                                               \
      }                                                                        \
    _Pragma("unroll")                                                          \
    for (int r = 0; r < 4; r++) {                                              \
      _Pragma("unroll")                                                        \
      for (int off = 1; off < 16; off <<= 1)                                   \
        pm[r] = fmaxf(pm[r], __shfl_xor(pm[r], off, 64));                      \
      float mn = fmaxf(mrow[r], pm[r]);                                        \
      float al = __expf(mrow[r] - mn);                                         \
      mrow[r] = mn;                                                            \
      float s = 0.f;                                                           \
      _Pragma("unroll")                                                        \
      for (int cg = 0; cg < 4; cg++) { p[cg][r] = __expf(p[cg][r] - mn); s += p[cg][r]; } \
      _Pragma("unroll")                                                        \
      for (int off = 1; off < 16; off <<= 1)                                   \
        s += __shfl_xor(s, off, 64);                                           \
      lrow[r] = lrow[r] * al + s;                                              \
      _Pragma("unroll")                                                        \
      for (int dg = 0; dg < 8; dg++) o[dg][r] *= al;                           \
    }                                                                          \
    _Pragma("unroll")                                                          \
    for (int cg = 0; cg < 4; cg++)                                             \
      _Pragma("unroll")                                                        \
      for (int r = 0; r < 4; r++) {                                            \
        int q = lg * 4 + r;                                                    \
        *((unsigned short*)((char*)&Plds[w][0] +                               \
            (q * 128 + (((cg * 16 + l15) * 2) ^ ((q & 7) << 4))))) = f2bf(p[cg][r]); \
      }                                                                        \
    asm volatile("s_waitcnt lgkmcnt(0)" ::: "memory");                         \
    __builtin_amdgcn_sched_barrier(0);                                         \
    __builtin_amdgcn_s_setprio(1);                                             \
    _Pragma("unroll")                                                          \
    for (int kc = 0; kc < 2; kc++) {                                           \
      bf16x8 pa = *(const bf16x8*)((char*)&Plds[w][0] +                        \
          (l15 * 128 + ((kc * 64 + lg * 16) ^ ((l15 & 7) << 4))));             \
      _Pragma("unroll")                                                        \
      for (int dg = 0; dg < 8; dg++) {                                         \
        int d = dg * 16 + l15;                                                 \
        bf16x8 vf = *(const bf16x8*)((char*)Vlds +                             \
            (d * 128 + ((kc * 64 + lg * 16) ^ ((d & 7) << 4))));               \
        o[dg] = __builtin_amdgcn_mfma_f32_16x16x32_bf16(pa, vf, o[dg], 0, 0, 0); \
      }                                                                        \
    }                                                                          \
    __builtin_amdgcn_s_setprio(0);                                             \
  } while (0)

__global__ __launch_bounds__(256, 2)
void attn_fwd(const unsigned short* __restrict__ qkv,
              const unsigned short* __restrict__ vT,
              unsigned short* __restrict__ out)
{
  __shared__ unsigned short Klds[64 * 128];   // [kv][d], XOR (kv&7)<<4
  __shared__ unsigned short Vlds[128 * 64];   // [d][kv], XOR (d&7)<<4
  __shared__ unsigned short Plds[4][16 * 64]; // per-wave P, XOR (q&7)<<4
  const int tid = threadIdx.x, lane = tid & 63, w = tid >> 6;
  const int l15 = lane & 15, lg = lane >> 4;

  // XCD swizzle: one head's K/V stays in one XCD's L2 (nwg=512, %8==0)
  const int nwg = gridDim.x * gridDim.y;
  int wg = blockIdx.y * gridDim.x + blockIdx.x;
  wg = (wg & 7) * (nwg >> 3) + (wg >> 3);
  const int ip = wg % 16;          // pair index: q-tiles ip and 31-ip
  const int bh = wg / 16;
  const int b = bh >> 4, hh = bh & 15;

  const int qbA = ip * 64, qbB = (31 - ip) * 64;
  const long base = (long)b * 2048 * 6144;
  const int qoff = hh * 128, koff = 2048 + hh * 128;
  const unsigned short* vTg = vT + (long)bh * (128 * 2048);

  bf16x8 qfA[4], qfB[4];
  {
    long qrA = qbA + w * 16 + l15, qrB = qbB + w * 16 + l15;
#pragma unroll
    for (int kc = 0; kc < 4; kc++) {
      qfA[kc] = *(const bf16x8*)(qkv + base + qrA * 6144 + qoff + kc * 32 + lg * 8);
      qfB[kc] = *(const bf16x8*)(qkv + base + qrB * 6144 + qoff + kc * 32 + lg * 8);
    }
  }
  f32x4 oA[8], oB[8];
#pragma unroll
  for (int dg = 0; dg < 8; dg++) {
    oA[dg] = f32x4{0.f, 0.f, 0.f, 0.f};
    oB[dg] = f32x4{0.f, 0.f, 0.f, 0.f};
  }
  float mA[4] = {-1e30f, -1e30f, -1e30f, -1e30f}, lA[4] = {0.f, 0.f, 0.f, 0.f};
  float mB[4] = {-1e30f, -1e30f, -1e30f, -1e30f}, lB[4] = {0.f, 0.f, 0.f, 0.f};
  const float scale = 0.08838834764831845f;  // 1/sqrt(128)

  const int s_st = tid >> 4, d0 = (tid & 15) * 8;   // K staging coords
  const int vrow = tid >> 3, vc = tid & 7;          // V staging coords

  const int nt = 32 - ip;   // tiles 0 .. 31-ip
  for (int t = 0; t < nt; t++) {
    const int kv0 = t * 64;
    // stage K tile [64 kv][128 d]
#pragma unroll
    for (int u = 0; u < 4; u++) {
      int srow = s_st + u * 16;
      uint4 kk = *(const uint4*)(qkv + base + (long)(kv0 + srow) * 6144 + koff + d0);
      *(uint4*)((char*)Klds + (srow * 256 + ((d0 * 2) ^ ((srow & 7) << 4)))) = kk;
    }
    // stage V^T tile [128 d][64 kv] (coalesced from vT)
#pragma unroll
    for (int u = 0; u < 4; u++) {
      int d = vrow + u * 32;
      uint4 vv = *(const uint4*)(vTg + (long)d * 2048 + kv0 + vc * 8);
      *(uint4*)((char*)Vlds + (d * 128 + ((vc * 16) ^ ((d & 7) << 4)))) = vv;
    }
    __syncthreads();

    if (t <= ip) QSTEP(qfA, mA, lA, oA, qbA, (t == ip));
    QSTEP(qfB, mB, lB, oB, qbB, (t == nt - 1));

    __syncthreads();
  }

#pragma unroll
  for (int r = 0; r < 4; r++) {
    float invA = 1.f / lA[r], invB = 1.f / lB[r];
    long rowA = (long)b * 2048 + qbA + w * 16 + lg * 4 + r;
    long rowB = (long)b * 2048 + qbB + w * 16 + lg * 4 + r;
#pragma unroll
    for (int dg = 0; dg < 8; dg++) {
      out[rowA * 2048 + hh * 128 + dg * 16 + l15] = f2bf(oA[dg][r] * invA);
      out[rowB * 2048 + hh * 128 + dg * 16 + l15] = f2bf(oB[dg][r] * invB);
    }
  }
}

// ---------------------------------------------------------------------------
extern "C" void kernel_launch(void* const* d_in, const int* in_sizes, int n_in,
                              void* d_out, int out_size, void* d_ws, size_t ws_size,
                              hipStream_t stream)
{
  const float* x     = (const float*)d_in[0];
  const float* w_qkv = (const float*)d_in[1];
  const float* w_out = (const float*)d_in[2];
  const float* g1    = (const float*)d_in[3];
  const float* g2    = (const float*)d_in[4];
  const float* w1    = (const float*)d_in[5];
  const float* w3    = (const float*)d_in[6];
  const float* w2    = (const float*)d_in[7];
  float* outp = (float*)d_out;
  char* ws = (char*)d_ws;

  // workspace arena (bytes)
  unsigned short* wT  = (unsigned short*)(ws);                 // 25,165,824 (max 6144x2048 bf16)
  unsigned short* y   = (unsigned short*)(ws + 25165824);      // 16,777,216
  unsigned short* qkv = (unsigned short*)(ws + 41943040);      // 50,331,648
  unsigned short* att = (unsigned short*)(ws + 92274688);      // 16,777,216
  float*          x1  = (float*)(ws + 109051904);              // 33,554,432
  unsigned short* s1  = (unsigned short*)(ws + 142606336);     // 46,137,344 -> end 188,743,680
  unsigned short* vTb = s1;                                    // vT (16.8MB), dead before s1 is written
  unsigned short* h   = qkv;                                   // reuse (qkv dead after attn)

  // x1 = x + attn(rmsnorm(x,g1)) @ w_out
  rmsnorm_bf16<<<4096, 256, 0, stream>>>(x, g1, y);
  transpose_w<<<dim3(6144 / 32, 2048 / 32), 256, 0, stream>>>(w_qkv, wT, 2048, 6144);
  gemm_bt<0><<<dim3(48, 32), 256, 0, stream>>>(y, wT, qkv, nullptr, nullptr, 4096, 6144, 2048);
  transpose_v<<<dim3(64, 4, 32), 256, 0, stream>>>(qkv, vTb);
  attn_fwd<<<dim3(16, 32), 256, 0, stream>>>(qkv, vTb, att);
  transpose_w<<<dim3(64, 64), 256, 0, stream>>>(w_out, wT, 2048, 2048);
  gemm_bt<3><<<dim3(16, 32), 256, 0, stream>>>(att, wT, x1, x, nullptr, 4096, 2048, 2048);

  // out = x1 + swiglu(rmsnorm(x1,g2))
  rmsnorm_bf16<<<4096, 256, 0, stream>>>(x1, g2, y);
  transpose_w<<<dim3(176, 64), 256, 0, stream>>>(w1, wT, 2048, 5632);
  gemm_bt<1><<<dim3(44, 32), 256, 0, stream>>>(y, wT, s1, nullptr, nullptr, 4096, 5632, 2048);
  transpose_w<<<dim3(176, 64), 256, 0, stream>>>(w3, wT, 2048, 5632);
  gemm_bt<2><<<dim3(44, 32), 256, 0, stream>>>(y, wT, h, nullptr, s1, 4096, 5632, 2048);
  transpose_w<<<dim3(64, 176), 256, 0, stream>>>(w2, wT, 5632, 2048);
  gemm_bt<3><<<dim3(16, 32), 256, 0, stream>>>(h, wT, outp, x1, nullptr, 4096, 2048, 5632);
}

// Round 4
// 715.354 us; speedup vs baseline: 3.0257x; 1.0016x over previous
//
#include <hip/hip_runtime.h>
#include <hip/hip_bf16.h>
#include <stdint.h>

// LLaMA block on MI355X. All matmuls in bf16 MFMA (16x16x32), fp32 accumulate.
// Dims fixed: B=2, S=2048, D=2048, H=16, hd=128, FF=5632.

typedef __attribute__((ext_vector_type(8))) short bf16x8;     // 8 bf16 = 4 VGPR
typedef __attribute__((ext_vector_type(8))) unsigned short u16x8;
typedef __attribute__((ext_vector_type(4))) float f32x4;

__device__ __forceinline__ unsigned short f2bf(float f) {
  union { float f; unsigned int u; } c; c.f = f;
  unsigned int u = c.u + 0x7fffu + ((c.u >> 16) & 1u);   // RNE
  return (unsigned short)(u >> 16);
}
__device__ __forceinline__ float bf2f(unsigned short h) {
  union { unsigned int u; float f; } c; c.u = ((unsigned int)h) << 16;
  return c.f;
}

// async global->LDS, 16B per lane; LDS dest is wave-uniform base + lane*16
__device__ __forceinline__ void gload16(const void* g, void* l) {
  __builtin_amdgcn_global_load_lds(
      (const __attribute__((address_space(1))) void*)g,
      (__attribute__((address_space(3))) void*)l, 16, 0, 0);
}

// ---------------------------------------------------------------------------
// RMSNorm: fp32 [rows][2048] -> bf16, y = x * rsqrt(mean(x^2)+eps) * g
// ---------------------------------------------------------------------------
__global__ __launch_bounds__(256)
void rmsnorm_bf16(const float* __restrict__ x, const float* __restrict__ g,
                  unsigned short* __restrict__ y)
{
  const long row = blockIdx.x;
  const float* xr = x + row * 2048;
  const int t = threadIdx.x;
  float4 a = *(const float4*)(xr + t * 8);
  float4 b = *(const float4*)(xr + t * 8 + 4);
  float ss = a.x*a.x + a.y*a.y + a.z*a.z + a.w*a.w
           + b.x*b.x + b.y*b.y + b.z*b.z + b.w*b.w;
#pragma unroll
  for (int off = 32; off >= 1; off >>= 1) ss += __shfl_xor(ss, off, 64);
  __shared__ float sm[4];
  if ((t & 63) == 0) sm[t >> 6] = ss;
  __syncthreads();
  float inv = rsqrtf((sm[0] + sm[1] + sm[2] + sm[3]) * (1.0f / 2048.0f) + 1e-6f);
  float4 ga = *(const float4*)(g + t * 8);
  float4 gb = *(const float4*)(g + t * 8 + 4);
  u16x8 ov;
  ov[0] = f2bf(a.x * inv * ga.x); ov[1] = f2bf(a.y * inv * ga.y);
  ov[2] = f2bf(a.z * inv * ga.z); ov[3] = f2bf(a.w * inv * ga.w);
  ov[4] = f2bf(b.x * inv * gb.x); ov[5] = f2bf(b.y * inv * gb.y);
  ov[6] = f2bf(b.z * inv * gb.z); ov[7] = f2bf(b.w * inv * gb.w);
  *(u16x8*)(y + row * 2048 + t * 8) = ov;
}

// ---------------------------------------------------------------------------
// Weight transpose + fp32->bf16: in [K][N] f32 -> out [N][K] bf16
// ---------------------------------------------------------------------------
__global__ __launch_bounds__(256)
void transpose_w(const float* __restrict__ in, unsigned short* __restrict__ outp,
                 int K, int N)
{
  __shared__ float tile[32][33];
  const int c0 = blockIdx.x * 32, r0 = blockIdx.y * 32;
  const int cx = threadIdx.x & 31, ry = threadIdx.x >> 5;
#pragma unroll
  for (int i = 0; i < 4; i++)
    tile[ry + i * 8][cx] = in[(long)(r0 + ry + i * 8) * N + c0 + cx];
  __syncthreads();
#pragma unroll
  for (int i = 0; i < 4; i++)
    outp[(long)(c0 + ry + i * 8) * K + r0 + cx] = f2bf(tile[cx][ry + i * 8]);
}

// ---------------------------------------------------------------------------
// V transpose: qkv V-section [b][s][h][d] -> vT [b][h][d][s]   (bf16)
// ---------------------------------------------------------------------------
__global__ __launch_bounds__(256)
void transpose_v(const unsigned short* __restrict__ qkv, unsigned short* __restrict__ vT)
{
  __shared__ unsigned short tile[32][34];   // +2 pad
  const int bh = blockIdx.z, b = bh >> 4, hh = bh & 15;
  const int s0 = blockIdx.x * 32, d0 = blockIdx.y * 32;
  const int cx = threadIdx.x & 31, ry = threadIdx.x >> 5;
  const unsigned short* src = qkv + (long)b * 2048 * 6144 + 4096 + hh * 128;
#pragma unroll
  for (int i = 0; i < 4; i++)
    tile[ry + i * 8][cx] = src[(long)(s0 + ry + i * 8) * 6144 + d0 + cx];
  __syncthreads();
  unsigned short* o = vT + ((long)bh * 128 + d0) * 2048 + s0;
#pragma unroll
  for (int i = 0; i < 4; i++)
    o[(long)(ry + i * 8) * 2048 + cx] = tile[cx][ry + i * 8];
}

// ---------------------------------------------------------------------------
// gemm256: C[M,N] = A[M,K]*Bt[N,K]^T, 256x256 tile, BK=64, 8 waves (2Mx4N),
// 8-phase schedule (T2 swizzle + T3/T4 counted vmcnt + T5 setprio).
// LDS 128KB: per buffer {A,B} x kk-halves [256][32] bf16 regions; each phase
// stages exactly the region freed by the previous phase; vmcnt(6) at ph4/ph8.
// EPI: 0=bf16, 1=silu->bf16, 2=mul(mulsrc)->bf16, 3=+res(fp32)->fp32.
// ---------------------------------------------------------------------------
#define PH_BAR __builtin_amdgcn_s_barrier()
#define LGKM0 asm volatile("s_waitcnt lgkmcnt(0)" ::: "memory")
#define VM6 asm volatile("s_waitcnt vmcnt(6)" ::: "memory")
#define VM0 asm volatile("s_waitcnt vmcnt(0)" ::: "memory")

#define REG_A(buf, kk) ((buf) * 65536 + (kk) * 16384)
#define REG_B(buf, kk) (32768 + (buf) * 65536 + (kk) * 16384)

#define LDA4(buf, kk, mg) { \
  a[0] = *(const bf16x8*)(L + REG_A(buf, kk) + aoff + ((mg) + 0) * 1024); \
  a[1] = *(const bf16x8*)(L + REG_A(buf, kk) + aoff + ((mg) + 1) * 1024); \
  a[2] = *(const bf16x8*)(L + REG_A(buf, kk) + aoff + ((mg) + 2) * 1024); \
  a[3] = *(const bf16x8*)(L + REG_A(buf, kk) + aoff + ((mg) + 3) * 1024); }

#define LDB4(buf, kk) { \
  b[0] = *(const bf16x8*)(L + REG_B(buf, kk) + boff + 0 * 1024); \
  b[1] = *(const bf16x8*)(L + REG_B(buf, kk) + boff + 1 * 1024); \
  b[2] = *(const bf16x8*)(L + REG_B(buf, kk) + boff + 2 * 1024); \
  b[3] = *(const bf16x8*)(L + REG_B(buf, kk) + boff + 3 * 1024); }

#define MM16(mg) { \
  __builtin_amdgcn_s_setprio(1); \
  _Pragma("unroll") for (int j = 0; j < 4; j++) \
    _Pragma("unroll") for (int n = 0; n < 4; n++) \
      acc[(mg) + j][n] = __builtin_amdgcn_mfma_f32_16x16x32_bf16(a[j], b[n], acc[(mg) + j][n], 0, 0, 0); \
  __builtin_amdgcn_s_setprio(0); }

#define STGA(buf, kk, tt) { \
  gload16(As + (long)(tt) * 64 + (kk) * 32,         L + REG_A(buf, kk) + sdst); \
  gload16(As + rstep + (long)(tt) * 64 + (kk) * 32, L + REG_A(buf, kk) + 8192 + sdst); }
#define STGB(buf, kk, tt) { \
  gload16(Bs + (long)(tt) * 64 + (kk) * 32,         L + REG_B(buf, kk) + sdst); \
  gload16(Bs + rstep + (long)(tt) * 64 + (kk) * 32, L + REG_B(buf, kk) + 8192 + sdst); }

template<int EPI>
__global__ __launch_bounds__(512, 2)
void gemm256(const unsigned short* __restrict__ A,
             const unsigned short* __restrict__ Bt,
             void* __restrict__ Cout,
             const float* __restrict__ res,
             const unsigned short* __restrict__ mulsrc,
             int M, int N, int K)
{
  __shared__ alignas(16) char L[131072];
  const int tid = threadIdx.x;
  const int lane = tid & 63, wave = tid >> 6;
  const int wr = wave >> 2, wc = wave & 3;
  const int l15 = lane & 15, lg = lane >> 4;

  // XCD swizzle (all grids have nwg % 8 == 0)
  const int nwg = gridDim.x * gridDim.y;
  int wg = blockIdx.y * gridDim.x + blockIdx.x;
  wg = (wg & 7) * (nwg >> 3) + (wg >> 3);
  const int bx = wg % gridDim.x, by = wg / gridDim.x;
  const long m0 = (long)by * 256, n0 = (long)bx * 256;

  f32x4 acc[8][4];
#pragma unroll
  for (int m = 0; m < 8; m++)
#pragma unroll
    for (int n = 0; n < 4; n++) acc[m][n] = f32x4{0.f, 0.f, 0.f, 0.f};

  // staging: chunkidx(i) = i*512 + tid; row = ck>>2, cc = ck&3 (16B chunks of a
  // [256][32] kk-half); source pre-swizzled so swizzled ds_reads see linear data
  const int row0 = tid >> 2, cc = tid & 3;
  const int csw = cc ^ ((row0 >> 1) & 3);
  const unsigned short* As = A + (m0 + row0) * (long)K + csw * 8;
  const unsigned short* Bs = Bt + (n0 + row0) * (long)K + csw * 8;
  const long rstep = (long)128 * K;
  const int sdst = wave * 1024;   // + region + i*8192 (bytes)

  // fragment ds_read offsets (bytes within region), swizzle matches staging
  const int swz = (lg ^ ((l15 >> 1) & 3)) << 4;
  const int aoff = wr * 8192 + l15 * 64 + swz;   // + m*1024
  const int boff = wc * 4096 + l15 * 64 + swz;   // + n*1024

  const int nkt = K >> 6, nit = nkt >> 1;

  // prologue: stage T0 fully + T1 {Bk0, Ak0, Bk1} in steady-state issue order
  STGB(0, 0, 0); STGA(0, 0, 0); STGB(0, 1, 0); STGA(0, 1, 0);
  STGB(1, 0, 1); STGA(1, 0, 1); STGB(1, 1, 1);
  VM6;                                   // forces T0's 4 halves
  PH_BAR;
  __builtin_amdgcn_sched_barrier(0);

  for (int it = 0; it < nit; ++it) {
    const int T = 2 * it;
    const bool full = (it < nit - 1);
    bf16x8 a[4], b[4];
    // ph1: compute T kk0 m0-3; stage buf1.A-k1 <- A(T+1)k1
    LDB4(0, 0) LDA4(0, 0, 0)
    STGA(1, 1, T + 1)
    PH_BAR; LGKM0;
    MM16(0)
    PH_BAR;
    // ph2: T kk0 m4-7; stage buf0.B-k0 <- B(T+2)k0
    LDA4(0, 0, 4)
    if (full) STGB(0, 0, T + 2)
    PH_BAR; LGKM0;
    MM16(4)
    PH_BAR;
    // ph3: T kk1 m0-3; stage buf0.A-k0 <- A(T+2)k0
    LDB4(0, 1) LDA4(0, 1, 0)
    if (full) STGA(0, 0, T + 2)
    PH_BAR; LGKM0;
    MM16(0)
    PH_BAR;
    // ph4: T kk1 m4-7; stage buf0.B-k1 <- B(T+2)k1; vmcnt gate for buf1 reads
    LDA4(0, 1, 4)
    if (full) STGB(0, 1, T + 2)
    PH_BAR; LGKM0;
    MM16(4)
    if (full) { VM6; } else { VM0; }
    PH_BAR;
    __builtin_amdgcn_sched_barrier(0);
    // ph5: T+1 kk0 m0-3; stage buf0.A-k1 <- A(T+2)k1
    LDB4(1, 0) LDA4(1, 0, 0)
    if (full) STGA(0, 1, T + 2)
    PH_BAR; LGKM0;
    MM16(0)
    PH_BAR;
    // ph6: T+1 kk0 m4-7; stage buf1.B-k0 <- B(T+3)k0
    LDA4(1, 0, 4)
    if (full) STGB(1, 0, T + 3)
    PH_BAR; LGKM0;
    MM16(4)
    PH_BAR;
    // ph7: T+1 kk1 m0-3; stage buf1.A-k0 <- A(T+3)k0
    LDB4(1, 1) LDA4(1, 1, 0)
    if (full) STGA(1, 0, T + 3)
    PH_BAR; LGKM0;
    MM16(0)
    PH_BAR;
    // ph8: T+1 kk1 m4-7; stage buf1.B-k1 <- B(T+3)k1; vmcnt gate for next buf0
    LDA4(1, 1, 4)
    if (full) STGB(1, 1, T + 3)
    PH_BAR; LGKM0;
    MM16(4)
    if (full) { VM6; }
    PH_BAR;
    __builtin_amdgcn_sched_barrier(0);
  }

  if (EPI == 3) {
#pragma unroll
    for (int m = 0; m < 8; m++)
#pragma unroll
      for (int n = 0; n < 4; n++)
#pragma unroll
        for (int r = 0; r < 4; r++) {
          long row = m0 + wr * 128 + m * 16 + lg * 4 + r;
          long col = n0 + wc * 64 + n * 16 + l15;
          ((float*)Cout)[row * N + col] = acc[m][n][r] + res[row * N + col];
        }
    return;
  }

  // bf16 epilogues: stage 256x256 C tile in (drained) LDS, 16B/lane stores
#pragma unroll
  for (int m = 0; m < 8; m++)
#pragma unroll
    for (int n = 0; n < 4; n++)
#pragma unroll
      for (int r = 0; r < 4; r++) {
        float v = acc[m][n][r];
        if (EPI == 1) v = v / (1.f + __expf(-v));
        *(unsigned short*)(L + (wr * 128 + m * 16 + lg * 4 + r) * 512
                             + (wc * 64 + n * 16 + l15) * 2) = f2bf(v);
      }
  __syncthreads();
#pragma unroll
  for (int rnd = 0; rnd < 16; rnd++) {
    int id = tid + rnd * 512;
    int row = id >> 5, c = (id & 31) * 8;
    u16x8 v = *(const u16x8*)(L + row * 512 + c * 2);
    long grow = m0 + row, gcol = n0 + c;
    if (EPI == 2) {
      u16x8 mm = *(const u16x8*)(mulsrc + grow * N + gcol);
#pragma unroll
      for (int j = 0; j < 8; j++) v[j] = f2bf(bf2f(v[j]) * bf2f(mm[j]));
    }
    *(u16x8*)((unsigned short*)Cout + grow * N + gcol) = v;
  }
}

// ---------------------------------------------------------------------------
// GEMM (m97 128x128 structure) kept for N=2048 outputs (grid 512 = 2/CU).
// EPI as above.
// ---------------------------------------------------------------------------
template<int EPI>
__global__ __launch_bounds__(256)
void gemm_bt(const unsigned short* __restrict__ A,
             const unsigned short* __restrict__ Bt,
             void* __restrict__ Cout,
             const float* __restrict__ res,
             const unsigned short* __restrict__ mulsrc,
             int M, int N, int K)
{
  __shared__ unsigned short lds[2 * 128 * 64];
  const int tid = threadIdx.x;
  const int lane = tid & 63, wave = tid >> 6;
  const int wr = wave >> 1, wc = wave & 1;
  const int l15 = lane & 15, lg = lane >> 4;

  const int nwg = gridDim.x * gridDim.y;
  int wg = blockIdx.y * gridDim.x + blockIdx.x;
  wg = (wg & 7) * (nwg >> 3) + (wg >> 3);
  const int bx = wg % gridDim.x, by = wg / gridDim.x;
  const long m0 = (long)by * 128, n0 = (long)bx * 128;

  f32x4 acc[4][4];
#pragma unroll
  for (int m = 0; m < 4; m++)
#pragma unroll
    for (int n = 0; n < 4; n++) acc[m][n] = f32x4{0.f, 0.f, 0.f, 0.f};

  const int rsub = lane >> 3;
  const int csw = (lane & 7) ^ rsub;
  const unsigned short* Ab = A + (m0 + wave * 32 + rsub) * (long)K + csw * 8;
  const unsigned short* Bb = Bt + (n0 + wave * 32 + rsub) * (long)K + csw * 8;
  unsigned short* Al = lds + wave * 2048;
  unsigned short* Bl = lds + 8192 + wave * 2048;

  for (int kt = 0; kt < K; kt += 64) {
    __syncthreads();
#pragma unroll
    for (int i = 0; i < 4; i++) {
      gload16(Ab + (long)(i * 8) * K + kt, Al + i * 512);
      gload16(Bb + (long)(i * 8) * K + kt, Bl + i * 512);
    }
    __syncthreads();
#pragma unroll
    for (int kc = 0; kc < 2; kc++) {
      bf16x8 af[4], bfr[4];
#pragma unroll
      for (int m = 0; m < 4; m++) {
        int row = wr * 64 + m * 16 + l15;
        int off = row * 128 + ((kc * 64 + lg * 16) ^ ((row & 7) << 4));
        af[m] = *(const bf16x8*)((const char*)lds + off);
      }
#pragma unroll
      for (int n = 0; n < 4; n++) {
        int row = wc * 64 + n * 16 + l15;
        int off = 16384 + row * 128 + ((kc * 64 + lg * 16) ^ ((row & 7) << 4));
        bfr[n] = *(const bf16x8*)((const char*)lds + off);
      }
#pragma unroll
      for (int m = 0; m < 4; m++)
#pragma unroll
        for (int n = 0; n < 4; n++)
          acc[m][n] = __builtin_amdgcn_mfma_f32_16x16x32_bf16(af[m], bfr[n], acc[m][n], 0, 0, 0);
    }
  }

  if (EPI == 3) {
#pragma unroll
    for (int m = 0; m < 4; m++)
#pragma unroll
      for (int n = 0; n < 4; n++)
#pragma unroll
        for (int r = 0; r < 4; r++) {
          long row = m0 + wr * 64 + m * 16 + lg * 4 + r;
          long col = n0 + wc * 64 + n * 16 + l15;
          ((float*)Cout)[row * N + col] = acc[m][n][r] + res[row * N + col];
        }
    return;
  }

  __syncthreads();
  unsigned short* Cl = lds;
#pragma unroll
  for (int m = 0; m < 4; m++)
#pragma unroll
    for (int n = 0; n < 4; n++)
#pragma unroll
      for (int r = 0; r < 4; r++) {
        float v = acc[m][n][r];
        if (EPI == 1) v = v / (1.f + __expf(-v));
        Cl[(wr * 64 + m * 16 + lg * 4 + r) * 128 + wc * 64 + n * 16 + l15] = f2bf(v);
      }
  __syncthreads();
#pragma unroll
  for (int r8 = 0; r8 < 8; r8++) {
    int id = tid + r8 * 256;
    int row = id >> 4, c = (id & 15) * 8;
    long grow = m0 + row, gcol = n0 + c;
    u16x8 v = *(const u16x8*)(Cl + row * 128 + c);
    if (EPI == 2) {
      u16x8 mm = *(const u16x8*)(mulsrc + grow * N + gcol);
#pragma unroll
      for (int j = 0; j < 8; j++) v[j] = f2bf(bf2f(v[j]) * bf2f(mm[j]));
    }
    *(u16x8*)((unsigned short*)Cout + grow * N + gcol) = v;
  }
}

// ---------------------------------------------------------------------------
// Causal flash attention, paired q-tiles for load balance.
// ---------------------------------------------------------------------------
#define QSTEP(qf, mrow, lrow, o, qb, isdiag) do {                              \
    f32x4 sacc[4];                                                             \
    __builtin_amdgcn_s_setprio(1);                                             \
    _Pragma("unroll")                                                          \
    for (int cg = 0; cg < 4; cg++) {                                           \
      f32x4 a = f32x4{0.f, 0.f, 0.f, 0.f};                                     \
      _Pragma("unroll")                                                        \
      for (int kc = 0; kc < 4; kc++) {                                         \
        int krow = cg * 16 + l15;                                              \
        bf16x8 kf = *(const bf16x8*)((char*)Klds +                             \
            (krow * 256 + ((kc * 64 + lg * 16) ^ ((krow & 7) << 4))));         \
        a = __builtin_amdgcn_mfma_f32_16x16x32_bf16(qf[kc], kf, a, 0, 0, 0);   \
      }                                                                        \
      sacc[cg] = a;                                                            \
    }                                                                          \
    __builtin_amdgcn_s_setprio(0);                                             \
    float p[4][4], pm[4];                                                      \
    _Pragma("unroll")                                                          \
    for (int r = 0; r < 4; r++) pm[r] = -1e30f;                                \
    _Pragma("unroll")                                                          \
    for (int cg = 0; cg < 4; cg++)                                             \
      _Pragma("unroll")                                                        \
      for (int r = 0; r < 4; r++) {                                            \
        float v = sacc[cg][r] * scale;                                         \
        if (isdiag) {                                                          \
          int kvg = kv0 + cg * 16 + l15;                                       \
          int qg = qb + w * 16 + lg * 4 + r;                                   \
          if (kvg > qg) v = -1e30f;                                            \
        }                                                                      \
        p[cg][r] = v;                                                          \
        pm[r] = fmaxf(pm[r], v);                                               \
      }                                                                        \
    _Pragma("unroll")                                                          \
    for (int r = 0; r < 4; r++) {                                              \
      _Pragma("unroll")                                                        \
      for (int off = 1; off < 16; off <<= 1)                                   \
        pm[r] = fmaxf(pm[r], __shfl_xor(pm[r], off, 64));                      \
      float mn = fmaxf(mrow[r], pm[r]);                                        \
      float al = __expf(mrow[r] - mn);                                         \
      mrow[r] = mn;                                                            \
      float s = 0.f;                                                           \
      _Pragma("unroll")                                                        \
      for (int cg = 0; cg < 4; cg++) { p[cg][r] = __expf(p[cg][r] - mn); s += p[cg][r]; } \
      _Pragma("unroll")                                                        \
      for (int off = 1; off < 16; off <<= 1)                                   \
        s += __shfl_xor(s, off, 64);                                           \
      lrow[r] = lrow[r] * al + s;                                              \
      _Pragma("unroll")                                                        \
      for (int dg = 0; dg < 8; dg++) o[dg][r] *= al;                           \
    }                                                                          \
    _Pragma("unroll")                                                          \
    for (int cg = 0; cg < 4; cg++)                                             \
      _Pragma("unroll")                                                        \
      for (int r = 0; r < 4; r++) {                                            \
        int q = lg * 4 + r;                                                    \
        *((unsigned short*)((char*)&Plds[w][0] +                               \
            (q * 128 + (((cg * 16 + l15) * 2) ^ ((q & 7) << 4))))) = f2bf(p[cg][r]); \
      }                                                                        \
    asm volatile("s_waitcnt lgkmcnt(0)" ::: "memory");                         \
    __builtin_amdgcn_sched_barrier(0);                                         \
    __builtin_amdgcn_s_setprio(1);                                             \
    _Pragma("unroll")                                                          \
    for (int kc = 0; kc < 2; kc++) {                                           \
      bf16x8 pa = *(const bf16x8*)((char*)&Plds[w][0] +                        \
          (l15 * 128 + ((kc * 64 + lg * 16) ^ ((l15 & 7) << 4))));             \
      _Pragma("unroll")                                                        \
      for (int dg = 0; dg < 8; dg++) {                                         \
        int d = dg * 16 + l15;                                                 \
        bf16x8 vf = *(const bf16x8*)((char*)Vlds +                             \
            (d * 128 + ((kc * 64 + lg * 16) ^ ((d & 7) << 4))));               \
        o[dg] = __builtin_amdgcn_mfma_f32_16x16x32_bf16(pa, vf, o[dg], 0, 0, 0); \
      }                                                                        \
    }                                                                          \
    __builtin_amdgcn_s_setprio(0);                                             \
  } while (0)

__global__ __launch_bounds__(256, 2)
void attn_fwd(const unsigned short* __restrict__ qkv,
              const unsigned short* __restrict__ vT,
              unsigned short* __restrict__ out)
{
  __shared__ unsigned short Klds[64 * 128];
  __shared__ unsigned short Vlds[128 * 64];
  __shared__ unsigned short Plds[4][16 * 64];
  const int tid = threadIdx.x, lane = tid & 63, w = tid >> 6;
  const int l15 = lane & 15, lg = lane >> 4;

  const int nwg = gridDim.x * gridDim.y;
  int wg = blockIdx.y * gridDim.x + blockIdx.x;
  wg = (wg & 7) * (nwg >> 3) + (wg >> 3);
  const int ip = wg % 16;
  const int bh = wg / 16;
  const int b = bh >> 4, hh = bh & 15;

  const int qbA = ip * 64, qbB = (31 - ip) * 64;
  const long base = (long)b * 2048 * 6144;
  const int qoff = hh * 128, koff = 2048 + hh * 128;
  const unsigned short* vTg = vT + (long)bh * (128 * 2048);

  bf16x8 qfA[4], qfB[4];
  {
    long qrA = qbA + w * 16 + l15, qrB = qbB + w * 16 + l15;
#pragma unroll
    for (int kc = 0; kc < 4; kc++) {
      qfA[kc] = *(const bf16x8*)(qkv + base + qrA * 6144 + qoff + kc * 32 + lg * 8);
      qfB[kc] = *(const bf16x8*)(qkv + base + qrB * 6144 + qoff + kc * 32 + lg * 8);
    }
  }
  f32x4 oA[8], oB[8];
#pragma unroll
  for (int dg = 0; dg < 8; dg++) {
    oA[dg] = f32x4{0.f, 0.f, 0.f, 0.f};
    oB[dg] = f32x4{0.f, 0.f, 0.f, 0.f};
  }
  float mA[4] = {-1e30f, -1e30f, -1e30f, -1e30f}, lA[4] = {0.f, 0.f, 0.f, 0.f};
  float mB[4] = {-1e30f, -1e30f, -1e30f, -1e30f}, lB[4] = {0.f, 0.f, 0.f, 0.f};
  const float scale = 0.08838834764831845f;

  const int s_st = tid >> 4, d0 = (tid & 15) * 8;
  const int vrow = tid >> 3, vc = tid & 7;

  const int nt = 32 - ip;
  for (int t = 0; t < nt; t++) {
    const int kv0 = t * 64;
#pragma unroll
    for (int u = 0; u < 4; u++) {
      int srow = s_st + u * 16;
      uint4 kk = *(const uint4*)(qkv + base + (long)(kv0 + srow) * 6144 + koff + d0);
      *(uint4*)((char*)Klds + (srow * 256 + ((d0 * 2) ^ ((srow & 7) << 4)))) = kk;
    }
#pragma unroll
    for (int u = 0; u < 4; u++) {
      int d = vrow + u * 32;
      uint4 vv = *(const uint4*)(vTg + (long)d * 2048 + kv0 + vc * 8);
      *(uint4*)((char*)Vlds + (d * 128 + ((vc * 16) ^ ((d & 7) << 4)))) = vv;
    }
    __syncthreads();

    if (t <= ip) QSTEP(qfA, mA, lA, oA, qbA, (t == ip));
    QSTEP(qfB, mB, lB, oB, qbB, (t == nt - 1));

    __syncthreads();
  }

#pragma unroll
  for (int r = 0; r < 4; r++) {
    float invA = 1.f / lA[r], invB = 1.f / lB[r];
    long rowA = (long)b * 2048 + qbA + w * 16 + lg * 4 + r;
    long rowB = (long)b * 2048 + qbB + w * 16 + lg * 4 + r;
#pragma unroll
    for (int dg = 0; dg < 8; dg++) {
      out[rowA * 2048 + hh * 128 + dg * 16 + l15] = f2bf(oA[dg][r] * invA);
      out[rowB * 2048 + hh * 128 + dg * 16 + l15] = f2bf(oB[dg][r] * invB);
    }
  }
}

// ---------------------------------------------------------------------------
extern "C" void kernel_launch(void* const* d_in, const int* in_sizes, int n_in,
                              void* d_out, int out_size, void* d_ws, size_t ws_size,
                              hipStream_t stream)
{
  const float* x     = (const float*)d_in[0];
  const float* w_qkv = (const float*)d_in[1];
  const float* w_out = (const float*)d_in[2];
  const float* g1    = (const float*)d_in[3];
  const float* g2    = (const float*)d_in[4];
  const float* w1    = (const float*)d_in[5];
  const float* w3    = (const float*)d_in[6];
  const float* w2    = (const float*)d_in[7];
  float* outp = (float*)d_out;
  char* ws = (char*)d_ws;

  unsigned short* wT  = (unsigned short*)(ws);                 // 25,165,824
  unsigned short* y   = (unsigned short*)(ws + 25165824);      // 16,777,216
  unsigned short* qkv = (unsigned short*)(ws + 41943040);      // 50,331,648
  unsigned short* att = (unsigned short*)(ws + 92274688);      // 16,777,216
  float*          x1  = (float*)(ws + 109051904);              // 33,554,432
  unsigned short* s1  = (unsigned short*)(ws + 142606336);     // 46,137,344
  unsigned short* vTb = s1;                                    // vT (16.8MB), dead before s1
  unsigned short* h   = qkv;                                   // reuse after attn

  // x1 = x + attn(rmsnorm(x,g1)) @ w_out
  rmsnorm_bf16<<<4096, 256, 0, stream>>>(x, g1, y);
  transpose_w<<<dim3(192, 64), 256, 0, stream>>>(w_qkv, wT, 2048, 6144);
  gemm256<0><<<dim3(24, 16), 512, 0, stream>>>(y, wT, qkv, nullptr, nullptr, 4096, 6144, 2048);
  transpose_v<<<dim3(64, 4, 32), 256, 0, stream>>>(qkv, vTb);
  attn_fwd<<<dim3(16, 32), 256, 0, stream>>>(qkv, vTb, att);
  transpose_w<<<dim3(64, 64), 256, 0, stream>>>(w_out, wT, 2048, 2048);
  gemm_bt<3><<<dim3(16, 32), 256, 0, stream>>>(att, wT, x1, x, nullptr, 4096, 2048, 2048);

  // out = x1 + swiglu(rmsnorm(x1,g2))
  rmsnorm_bf16<<<4096, 256, 0, stream>>>(x1, g2, y);
  transpose_w<<<dim3(176, 64), 256, 0, stream>>>(w1, wT, 2048, 5632);
  gemm256<1><<<dim3(22, 16), 512, 0, stream>>>(y, wT, s1, nullptr, nullptr, 4096, 5632, 2048);
  transpose_w<<<dim3(176, 64), 256, 0, stream>>>(w3, wT, 2048, 5632);
  gemm256<2><<<dim3(22, 16), 512, 0, stream>>>(y, wT, h, nullptr, s1, 4096, 5632, 2048);
  transpose_w<<<dim3(64, 176), 256, 0, stream>>>(w2, wT, 5632, 2048);
  gemm_bt<3><<<dim3(16, 32), 256, 0, stream>>>(h, wT, outp, x1, nullptr, 4096, 2048, 5632);
}

// Round 5
// 708.939 us; speedup vs baseline: 3.0531x; 1.0090x over previous
//
#include <hip/hip_runtime.h>
#include <hip/hip_bf16.h>
#include <stdint.h>

// LLaMA block on MI355X. All matmuls in bf16 MFMA (16x16x32), fp32 accumulate.
// Dims fixed: B=2, S=2048, D=2048, H=16, hd=128, FF=5632.

typedef __attribute__((ext_vector_type(8))) short bf16x8;     // 8 bf16 = 4 VGPR
typedef __attribute__((ext_vector_type(8))) unsigned short u16x8;
typedef __attribute__((ext_vector_type(4))) float f32x4;

__device__ __forceinline__ unsigned short f2bf(float f) {
  union { float f; unsigned int u; } c; c.f = f;
  unsigned int u = c.u + 0x7fffu + ((c.u >> 16) & 1u);   // RNE
  return (unsigned short)(u >> 16);
}
__device__ __forceinline__ float bf2f(unsigned short h) {
  union { unsigned int u; float f; } c; c.u = ((unsigned int)h) << 16;
  return c.f;
}

// async global->LDS, 16B per lane; LDS dest is wave-uniform base + lane*16
__device__ __forceinline__ void gload16(const void* g, void* l) {
  __builtin_amdgcn_global_load_lds(
      (const __attribute__((address_space(1))) void*)g,
      (__attribute__((address_space(3))) void*)l, 16, 0, 0);
}

// ---------------------------------------------------------------------------
// RMSNorm: fp32 [rows][2048] -> bf16, y = x * rsqrt(mean(x^2)+eps) * g
// ---------------------------------------------------------------------------
__global__ __launch_bounds__(256)
void rmsnorm_bf16(const float* __restrict__ x, const float* __restrict__ g,
                  unsigned short* __restrict__ y)
{
  const long row = blockIdx.x;
  const float* xr = x + row * 2048;
  const int t = threadIdx.x;
  float4 a = *(const float4*)(xr + t * 8);
  float4 b = *(const float4*)(xr + t * 8 + 4);
  float ss = a.x*a.x + a.y*a.y + a.z*a.z + a.w*a.w
           + b.x*b.x + b.y*b.y + b.z*b.z + b.w*b.w;
#pragma unroll
  for (int off = 32; off >= 1; off >>= 1) ss += __shfl_xor(ss, off, 64);
  __shared__ float sm[4];
  if ((t & 63) == 0) sm[t >> 6] = ss;
  __syncthreads();
  float inv = rsqrtf((sm[0] + sm[1] + sm[2] + sm[3]) * (1.0f / 2048.0f) + 1e-6f);
  float4 ga = *(const float4*)(g + t * 8);
  float4 gb = *(const float4*)(g + t * 8 + 4);
  u16x8 ov;
  ov[0] = f2bf(a.x * inv * ga.x); ov[1] = f2bf(a.y * inv * ga.y);
  ov[2] = f2bf(a.z * inv * ga.z); ov[3] = f2bf(a.w * inv * ga.w);
  ov[4] = f2bf(b.x * inv * gb.x); ov[5] = f2bf(b.y * inv * gb.y);
  ov[6] = f2bf(b.z * inv * gb.z); ov[7] = f2bf(b.w * inv * gb.w);
  *(u16x8*)(y + row * 2048 + t * 8) = ov;
}

// ---------------------------------------------------------------------------
// Weight transpose + fp32->bf16: in [K][N] f32 -> out [N][K] bf16
// ---------------------------------------------------------------------------
__global__ __launch_bounds__(256)
void transpose_w(const float* __restrict__ in, unsigned short* __restrict__ outp,
                 int K, int N)
{
  __shared__ float tile[32][33];
  const int c0 = blockIdx.x * 32, r0 = blockIdx.y * 32;
  const int cx = threadIdx.x & 31, ry = threadIdx.x >> 5;
#pragma unroll
  for (int i = 0; i < 4; i++)
    tile[ry + i * 8][cx] = in[(long)(r0 + ry + i * 8) * N + c0 + cx];
  __syncthreads();
#pragma unroll
  for (int i = 0; i < 4; i++)
    outp[(long)(c0 + ry + i * 8) * K + r0 + cx] = f2bf(tile[cx][ry + i * 8]);
}

// ---------------------------------------------------------------------------
// V transpose: qkv V-section [b][s][h][d] -> vT [b][h][d][s]   (bf16)
// ---------------------------------------------------------------------------
__global__ __launch_bounds__(256)
void transpose_v(const unsigned short* __restrict__ qkv, unsigned short* __restrict__ vT)
{
  __shared__ unsigned short tile[32][34];   // +2 pad
  const int bh = blockIdx.z, b = bh >> 4, hh = bh & 15;
  const int s0 = blockIdx.x * 32, d0 = blockIdx.y * 32;
  const int cx = threadIdx.x & 31, ry = threadIdx.x >> 5;
  const unsigned short* src = qkv + (long)b * 2048 * 6144 + 4096 + hh * 128;
#pragma unroll
  for (int i = 0; i < 4; i++)
    tile[ry + i * 8][cx] = src[(long)(s0 + ry + i * 8) * 6144 + d0 + cx];
  __syncthreads();
  unsigned short* o = vT + ((long)bh * 128 + d0) * 2048 + s0;
#pragma unroll
  for (int i = 0; i < 4; i++)
    o[(long)(ry + i * 8) * 2048 + cx] = tile[cx][ry + i * 8];
}

// ---------------------------------------------------------------------------
// gemm256: C[M,N] = A[M,K]*Bt[N,K]^T, 256x256 tile, BK=64, 8 waves (2Mx4N),
// 8-phase schedule (T2 swizzle + T3/T4 counted vmcnt + T5 setprio), fully
// sched_barrier(0)-pinned phase pockets, branch-free steady loop + peeled
// drain iteration. LDS 128KB = 2buf x {A,B} x kk-half [256][32]bf16 regions.
// EPI: 0=bf16, 1=silu->bf16, 2=mul(mulsrc)->bf16, 3=+res(fp32)->fp32.
// ---------------------------------------------------------------------------
#define PH_BAR __builtin_amdgcn_s_barrier()
#define SB0 __builtin_amdgcn_sched_barrier(0)
#define LGKM0 asm volatile("s_waitcnt lgkmcnt(0)" ::: "memory")
#define VM6 asm volatile("s_waitcnt vmcnt(6)" ::: "memory")
#define VM0 asm volatile("s_waitcnt vmcnt(0)" ::: "memory")

#define REG_A(buf, kk) ((buf) * 65536 + (kk) * 16384)
#define REG_B(buf, kk) (32768 + (buf) * 65536 + (kk) * 16384)

#define LDA4(buf, kk, mg) { \
  a[0] = *(const bf16x8*)(L + REG_A(buf, kk) + aoff + ((mg) + 0) * 1024); \
  a[1] = *(const bf16x8*)(L + REG_A(buf, kk) + aoff + ((mg) + 1) * 1024); \
  a[2] = *(const bf16x8*)(L + REG_A(buf, kk) + aoff + ((mg) + 2) * 1024); \
  a[3] = *(const bf16x8*)(L + REG_A(buf, kk) + aoff + ((mg) + 3) * 1024); }

#define LDB4(buf, kk) { \
  b[0] = *(const bf16x8*)(L + REG_B(buf, kk) + boff + 0 * 1024); \
  b[1] = *(const bf16x8*)(L + REG_B(buf, kk) + boff + 1 * 1024); \
  b[2] = *(const bf16x8*)(L + REG_B(buf, kk) + boff + 2 * 1024); \
  b[3] = *(const bf16x8*)(L + REG_B(buf, kk) + boff + 3 * 1024); }

#define MM16(mg) { \
  __builtin_amdgcn_s_setprio(1); \
  _Pragma("unroll") for (int j = 0; j < 4; j++) \
    _Pragma("unroll") for (int n = 0; n < 4; n++) \
      acc[(mg) + j][n] = __builtin_amdgcn_mfma_f32_16x16x32_bf16(a[j], b[n], acc[(mg) + j][n], 0, 0, 0); \
  __builtin_amdgcn_s_setprio(0); }

#define STGA(buf, kk, tt) { \
  gload16(As + (long)(tt) * 64 + (kk) * 32,         L + REG_A(buf, kk) + sdst); \
  gload16(As + rstep + (long)(tt) * 64 + (kk) * 32, L + REG_A(buf, kk) + 8192 + sdst); }
#define STGB(buf, kk, tt) { \
  gload16(Bs + (long)(tt) * 64 + (kk) * 32,         L + REG_B(buf, kk) + sdst); \
  gload16(Bs + rstep + (long)(tt) * 64 + (kk) * 32, L + REG_B(buf, kk) + 8192 + sdst); }

#define NOSTG

// pinned phase: {LD||STG} | bar | lgkm0 | MFMA | [vm gate] | bar
#define PH(LDOPS, STGOPS, MG) \
  LDOPS STGOPS SB0; PH_BAR; LGKM0; SB0; MM16(MG); SB0; PH_BAR; SB0;
#define PHV(LDOPS, STGOPS, MG, VMOP) \
  LDOPS STGOPS SB0; PH_BAR; LGKM0; SB0; MM16(MG); SB0; VMOP; PH_BAR; SB0;

template<int EPI>
__global__ __launch_bounds__(512, 2)
void gemm256(const unsigned short* __restrict__ A,
             const unsigned short* __restrict__ Bt,
             void* __restrict__ Cout,
             const float* __restrict__ res,
             const unsigned short* __restrict__ mulsrc,
             int M, int N, int K)
{
  __shared__ alignas(16) char L[131072];
  const int tid = threadIdx.x;
  const int lane = tid & 63, wave = tid >> 6;
  const int wr = wave >> 2, wc = wave & 3;
  const int l15 = lane & 15, lg = lane >> 4;

  // XCD swizzle (all grids have nwg % 8 == 0)
  const int nwg = gridDim.x * gridDim.y;
  int wg = blockIdx.y * gridDim.x + blockIdx.x;
  wg = (wg & 7) * (nwg >> 3) + (wg >> 3);
  const int bx = wg % gridDim.x, by = wg / gridDim.x;
  const long m0 = (long)by * 256, n0 = (long)bx * 256;

  f32x4 acc[8][4];
#pragma unroll
  for (int m = 0; m < 8; m++)
#pragma unroll
    for (int n = 0; n < 4; n++) acc[m][n] = f32x4{0.f, 0.f, 0.f, 0.f};

  // staging: [256][32] kk-half regions; source pre-swizzled (involution) so
  // linear gload_lds dest + swizzled ds_read see consistent data (rule #21)
  const int row0 = tid >> 2, cc = tid & 3;
  const int csw = cc ^ ((row0 >> 1) & 3);
  const unsigned short* As = A + (m0 + row0) * (long)K + csw * 8;
  const unsigned short* Bs = Bt + (n0 + row0) * (long)K + csw * 8;
  const long rstep = (long)128 * K;
  const int sdst = wave * 1024;   // + region + i*8192 (bytes)

  // fragment ds_read offsets (bytes within region), swizzle matches staging
  const int swz = (lg ^ ((l15 >> 1) & 3)) << 4;
  const int aoff = wr * 8192 + l15 * 64 + swz;   // + m*1024
  const int boff = wc * 4096 + l15 * 64 + swz;   // + n*1024

  const int nkt = K >> 6;
  const int nit1 = (nkt >> 1) - 1;   // steady iterations; last pair peeled

  // prologue: stage T0 fully + T1 {Bk0, Ak0, Bk1} in steady-state issue order
  STGB(0, 0, 0); STGA(0, 0, 0); STGB(0, 1, 0); STGA(0, 1, 0);
  STGB(1, 0, 1); STGA(1, 0, 1); STGB(1, 1, 1);
  VM6;                                   // T0's 4 half-regions landed
  PH_BAR;
  SB0;

  for (int it = 0; it < nit1; ++it) {
    const int T = 2 * it;
    bf16x8 a[4], b[4];
    PH (LDB4(0,0) LDA4(0,0,0), STGA(1,1,T+1), 0)
    PH (LDA4(0,0,4),           STGB(0,0,T+2), 4)
    PH (LDB4(0,1) LDA4(0,1,0), STGA(0,0,T+2), 0)
    PHV(LDA4(0,1,4),           STGB(0,1,T+2), 4, VM6)
    PH (LDB4(1,0) LDA4(1,0,0), STGA(0,1,T+2), 0)
    PH (LDA4(1,0,4),           STGB(1,0,T+3), 4)
    PH (LDB4(1,1) LDA4(1,1,0), STGA(1,0,T+3), 0)
    PHV(LDA4(1,1,4),           STGB(1,1,T+3), 4, VM6)
  }
  { // peeled drain pair: T = nkt-2; only buf1.A-k1 (tile nkt-1) still to stage
    const int T = nkt - 2;
    bf16x8 a[4], b[4];
    PH (LDB4(0,0) LDA4(0,0,0), STGA(1,1,T+1), 0)
    PH (LDA4(0,0,4),           NOSTG,         4)
    PH (LDB4(0,1) LDA4(0,1,0), NOSTG,         0)
    PHV(LDA4(0,1,4),           NOSTG,         4, VM0)
    PH (LDB4(1,0) LDA4(1,0,0), NOSTG,         0)
    PH (LDA4(1,0,4),           NOSTG,         4)
    PH (LDB4(1,1) LDA4(1,1,0), NOSTG,         0)
    PH (LDA4(1,1,4),           NOSTG,         4)
  }

  if (EPI == 3) {
#pragma unroll
    for (int m = 0; m < 8; m++)
#pragma unroll
      for (int n = 0; n < 4; n++)
#pragma unroll
        for (int r = 0; r < 4; r++) {
          long row = m0 + wr * 128 + m * 16 + lg * 4 + r;
          long col = n0 + wc * 64 + n * 16 + l15;
          ((float*)Cout)[row * N + col] = acc[m][n][r] + res[row * N + col];
        }
    return;
  }

  // bf16 epilogues: stage 256x256 C tile in (drained) LDS, 16B/lane stores
  __syncthreads();
#pragma unroll
  for (int m = 0; m < 8; m++)
#pragma unroll
    for (int n = 0; n < 4; n++)
#pragma unroll
      for (int r = 0; r < 4; r++) {
        float v = acc[m][n][r];
        if (EPI == 1) v = v / (1.f + __expf(-v));
        *(unsigned short*)(L + (wr * 128 + m * 16 + lg * 4 + r) * 512
                             + (wc * 64 + n * 16 + l15) * 2) = f2bf(v);
      }
  __syncthreads();
#pragma unroll
  for (int rnd = 0; rnd < 16; rnd++) {
    int id = tid + rnd * 512;
    int row = id >> 5, c = (id & 31) * 8;
    u16x8 v = *(const u16x8*)(L + row * 512 + c * 2);
    long grow = m0 + row, gcol = n0 + c;
    if (EPI == 2) {
      u16x8 mm = *(const u16x8*)(mulsrc + grow * N + gcol);
#pragma unroll
      for (int j = 0; j < 8; j++) v[j] = f2bf(bf2f(v[j]) * bf2f(mm[j]));
    }
    *(u16x8*)((unsigned short*)Cout + grow * N + gcol) = v;
  }
}

// ---------------------------------------------------------------------------
// GEMM (m97 128x128 structure) kept for N=2048 outputs (grid 512 = 2/CU).
// ---------------------------------------------------------------------------
template<int EPI>
__global__ __launch_bounds__(256)
void gemm_bt(const unsigned short* __restrict__ A,
             const unsigned short* __restrict__ Bt,
             void* __restrict__ Cout,
             const float* __restrict__ res,
             const unsigned short* __restrict__ mulsrc,
             int M, int N, int K)
{
  __shared__ unsigned short lds[2 * 128 * 64];
  const int tid = threadIdx.x;
  const int lane = tid & 63, wave = tid >> 6;
  const int wr = wave >> 1, wc = wave & 1;
  const int l15 = lane & 15, lg = lane >> 4;

  const int nwg = gridDim.x * gridDim.y;
  int wg = blockIdx.y * gridDim.x + blockIdx.x;
  wg = (wg & 7) * (nwg >> 3) + (wg >> 3);
  const int bx = wg % gridDim.x, by = wg / gridDim.x;
  const long m0 = (long)by * 128, n0 = (long)bx * 128;

  f32x4 acc[4][4];
#pragma unroll
  for (int m = 0; m < 4; m++)
#pragma unroll
    for (int n = 0; n < 4; n++) acc[m][n] = f32x4{0.f, 0.f, 0.f, 0.f};

  const int rsub = lane >> 3;
  const int csw = (lane & 7) ^ rsub;
  const unsigned short* Ab = A + (m0 + wave * 32 + rsub) * (long)K + csw * 8;
  const unsigned short* Bb = Bt + (n0 + wave * 32 + rsub) * (long)K + csw * 8;
  unsigned short* Al = lds + wave * 2048;
  unsigned short* Bl = lds + 8192 + wave * 2048;

  for (int kt = 0; kt < K; kt += 64) {
    __syncthreads();
#pragma unroll
    for (int i = 0; i < 4; i++) {
      gload16(Ab + (long)(i * 8) * K + kt, Al + i * 512);
      gload16(Bb + (long)(i * 8) * K + kt, Bl + i * 512);
    }
    __syncthreads();
#pragma unroll
    for (int kc = 0; kc < 2; kc++) {
      bf16x8 af[4], bfr[4];
#pragma unroll
      for (int m = 0; m < 4; m++) {
        int row = wr * 64 + m * 16 + l15;
        int off = row * 128 + ((kc * 64 + lg * 16) ^ ((row & 7) << 4));
        af[m] = *(const bf16x8*)((const char*)lds + off);
      }
#pragma unroll
      for (int n = 0; n < 4; n++) {
        int row = wc * 64 + n * 16 + l15;
        int off = 16384 + row * 128 + ((kc * 64 + lg * 16) ^ ((row & 7) << 4));
        bfr[n] = *(const bf16x8*)((const char*)lds + off);
      }
#pragma unroll
      for (int m = 0; m < 4; m++)
#pragma unroll
        for (int n = 0; n < 4; n++)
          acc[m][n] = __builtin_amdgcn_mfma_f32_16x16x32_bf16(af[m], bfr[n], acc[m][n], 0, 0, 0);
    }
  }

  if (EPI == 3) {
#pragma unroll
    for (int m = 0; m < 4; m++)
#pragma unroll
      for (int n = 0; n < 4; n++)
#pragma unroll
        for (int r = 0; r < 4; r++) {
          long row = m0 + wr * 64 + m * 16 + lg * 4 + r;
          long col = n0 + wc * 64 + n * 16 + l15;
          ((float*)Cout)[row * N + col] = acc[m][n][r] + res[row * N + col];
        }
    return;
  }

  __syncthreads();
  unsigned short* Cl = lds;
#pragma unroll
  for (int m = 0; m < 4; m++)
#pragma unroll
    for (int n = 0; n < 4; n++)
#pragma unroll
      for (int r = 0; r < 4; r++) {
        float v = acc[m][n][r];
        if (EPI == 1) v = v / (1.f + __expf(-v));
        Cl[(wr * 64 + m * 16 + lg * 4 + r) * 128 + wc * 64 + n * 16 + l15] = f2bf(v);
      }
  __syncthreads();
#pragma unroll
  for (int r8 = 0; r8 < 8; r8++) {
    int id = tid + r8 * 256;
    int row = id >> 4, c = (id & 15) * 8;
    long grow = m0 + row, gcol = n0 + c;
    u16x8 v = *(const u16x8*)(Cl + row * 128 + c);
    if (EPI == 2) {
      u16x8 mm = *(const u16x8*)(mulsrc + grow * N + gcol);
#pragma unroll
      for (int j = 0; j < 8; j++) v[j] = f2bf(bf2f(v[j]) * bf2f(mm[j]));
    }
    *(u16x8*)((unsigned short*)Cout + grow * N + gcol) = v;
  }
}

// ---------------------------------------------------------------------------
// Causal flash attention, paired q-tiles for load balance.
// ---------------------------------------------------------------------------
#define QSTEP(qf, mrow, lrow, o, qb, isdiag) do {                              \
    f32x4 sacc[4];                                                             \
    __builtin_amdgcn_s_setprio(1);                                             \
    _Pragma("unroll")                                                          \
    for (int cg = 0; cg < 4; cg++) {                                           \
      f32x4 a = f32x4{0.f, 0.f, 0.f, 0.f};                                     \
      _Pragma("unroll")                                                        \
      for (int kc = 0; kc < 4; kc++) {                                         \
        int krow = cg * 16 + l15;                                              \
        bf16x8 kf = *(const bf16x8*)((char*)Klds +                             \
            (krow * 256 + ((kc * 64 + lg * 16) ^ ((krow & 7) << 4))));         \
        a = __builtin_amdgcn_mfma_f32_16x16x32_bf16(qf[kc], kf, a, 0, 0, 0);   \
      }                                                                        \
      sacc[cg] = a;                                                            \
    }                                                                          \
    __builtin_amdgcn_s_setprio(0);                                             \
    float p[4][4], pm[4];                                                      \
    _Pragma("unroll")                                                          \
    for (int r = 0; r < 4; r++) pm[r] = -1e30f;                                \
    _Pragma("unroll")                                                          \
    for (int cg = 0; cg < 4; cg++)                                             \
      _Pragma("unroll")                                                        \
      for (int r = 0; r < 4; r++) {                                            \
        float v = sacc[cg][r] * scale;                                         \
        if (isdiag) {                                                          \
          int kvg = kv0 + cg * 16 + l15;                                       \
          int qg = qb + w * 16 + lg * 4 + r;                                   \
          if (kvg > qg) v = -1e30f;                                            \
        }                                                                      \
        p[cg][r] = v;                                                          \
        pm[r] = fmaxf(pm[r], v);                                               \
      }                                                                        \
    _Pragma("unroll")                                                          \
    for (int r = 0; r < 4; r++) {                                              \
      _Pragma("unroll")                                                        \
      for (int off = 1; off < 16; off <<= 1)                                   \
        pm[r] = fmaxf(pm[r], __shfl_xor(pm[r], off, 64));                      \
      float mn = fmaxf(mrow[r], pm[r]);                                        \
      float al = __expf(mrow[r] - mn);                                         \
      mrow[r] = mn;                                                            \
      float s = 0.f;                                                           \
      _Pragma("unroll")                                                        \
      for (int cg = 0; cg < 4; cg++) { p[cg][r] = __expf(p[cg][r] - mn); s += p[cg][r]; } \
      _Pragma("unroll")                                                        \
      for (int off = 1; off < 16; off <<= 1)                                   \
        s += __shfl_xor(s, off, 64);                                           \
      lrow[r] = lrow[r] * al + s;                                              \
      _Pragma("unroll")                                                        \
      for (int dg = 0; dg < 8; dg++) o[dg][r] *= al;                           \
    }                                                                          \
    _Pragma("unroll")                                                          \
    for (int cg = 0; cg < 4; cg++)                                             \
      _Pragma("unroll")                                                        \
      for (int r = 0; r < 4; r++) {                                            \
        int q = lg * 4 + r;                                                    \
        *((unsigned short*)((char*)&Plds[w][0] +                               \
            (q * 128 + (((cg * 16 + l15) * 2) ^ ((q & 7) << 4))))) = f2bf(p[cg][r]); \
      }                                                                        \
    asm volatile("s_waitcnt lgkmcnt(0)" ::: "memory");                         \
    __builtin_amdgcn_sched_barrier(0);                                         \
    __builtin_amdgcn_s_setprio(1);                                             \
    _Pragma("unroll")                                                          \
    for (int kc = 0; kc < 2; kc++) {                                           \
      bf16x8 pa = *(const bf16x8*)((char*)&Plds[w][0] +                        \
          (l15 * 128 + ((kc * 64 + lg * 16) ^ ((l15 & 7) << 4))));             \
      _Pragma("unroll")                                                        \
      for (int dg = 0; dg < 8; dg++) {                                         \
        int d = dg * 16 + l15;                                                 \
        bf16x8 vf = *(const bf16x8*)((char*)Vlds +                             \
            (d * 128 + ((kc * 64 + lg * 16) ^ ((d & 7) << 4))));               \
        o[dg] = __builtin_amdgcn_mfma_f32_16x16x32_bf16(pa, vf, o[dg], 0, 0, 0); \
      }                                                                        \
    }                                                                          \
    __builtin_amdgcn_s_setprio(0);                                             \
  } while (0)

__global__ __launch_bounds__(256, 2)
void attn_fwd(const unsigned short* __restrict__ qkv,
              const unsigned short* __restrict__ vT,
              unsigned short* __restrict__ out)
{
  __shared__ unsigned short Klds[64 * 128];
  __shared__ unsigned short Vlds[128 * 64];
  __shared__ unsigned short Plds[4][16 * 64];
  const int tid = threadIdx.x, lane = tid & 63, w = tid >> 6;
  const int l15 = lane & 15, lg = lane >> 4;

  const int nwg = gridDim.x * gridDim.y;
  int wg = blockIdx.y * gridDim.x + blockIdx.x;
  wg = (wg & 7) * (nwg >> 3) + (wg >> 3);
  const int ip = wg % 16;
  const int bh = wg / 16;
  const int b = bh >> 4, hh = bh & 15;

  const int qbA = ip * 64, qbB = (31 - ip) * 64;
  const long base = (long)b * 2048 * 6144;
  const int qoff = hh * 128, koff = 2048 + hh * 128;
  const unsigned short* vTg = vT + (long)bh * (128 * 2048);

  bf16x8 qfA[4], qfB[4];
  {
    long qrA = qbA + w * 16 + l15, qrB = qbB + w * 16 + l15;
#pragma unroll
    for (int kc = 0; kc < 4; kc++) {
      qfA[kc] = *(const bf16x8*)(qkv + base + qrA * 6144 + qoff + kc * 32 + lg * 8);
      qfB[kc] = *(const bf16x8*)(qkv + base + qrB * 6144 + qoff + kc * 32 + lg * 8);
    }
  }
  f32x4 oA[8], oB[8];
#pragma unroll
  for (int dg = 0; dg < 8; dg++) {
    oA[dg] = f32x4{0.f, 0.f, 0.f, 0.f};
    oB[dg] = f32x4{0.f, 0.f, 0.f, 0.f};
  }
  float mA[4] = {-1e30f, -1e30f, -1e30f, -1e30f}, lA[4] = {0.f, 0.f, 0.f, 0.f};
  float mB[4] = {-1e30f, -1e30f, -1e30f, -1e30f}, lB[4] = {0.f, 0.f, 0.f, 0.f};
  const float scale = 0.08838834764831845f;

  const int s_st = tid >> 4, d0 = (tid & 15) * 8;
  const int vrow = tid >> 3, vc = tid & 7;

  const int nt = 32 - ip;
  for (int t = 0; t < nt; t++) {
    const int kv0 = t * 64;
#pragma unroll
    for (int u = 0; u < 4; u++) {
      int srow = s_st + u * 16;
      uint4 kk = *(const uint4*)(qkv + base + (long)(kv0 + srow) * 6144 + koff + d0);
      *(uint4*)((char*)Klds + (srow * 256 + ((d0 * 2) ^ ((srow & 7) << 4)))) = kk;
    }
#pragma unroll
    for (int u = 0; u < 4; u++) {
      int d = vrow + u * 32;
      uint4 vv = *(const uint4*)(vTg + (long)d * 2048 + kv0 + vc * 8);
      *(uint4*)((char*)Vlds + (d * 128 + ((vc * 16) ^ ((d & 7) << 4)))) = vv;
    }
    __syncthreads();

    if (t <= ip) QSTEP(qfA, mA, lA, oA, qbA, (t == ip));
    QSTEP(qfB, mB, lB, oB, qbB, (t == nt - 1));

    __syncthreads();
  }

#pragma unroll
  for (int r = 0; r < 4; r++) {
    float invA = 1.f / lA[r], invB = 1.f / lB[r];
    long rowA = (long)b * 2048 + qbA + w * 16 + lg * 4 + r;
    long rowB = (long)b * 2048 + qbB + w * 16 + lg * 4 + r;
#pragma unroll
    for (int dg = 0; dg < 8; dg++) {
      out[rowA * 2048 + hh * 128 + dg * 16 + l15] = f2bf(oA[dg][r] * invA);
      out[rowB * 2048 + hh * 128 + dg * 16 + l15] = f2bf(oB[dg][r] * invB);
    }
  }
}

// ---------------------------------------------------------------------------
extern "C" void kernel_launch(void* const* d_in, const int* in_sizes, int n_in,
                              void* d_out, int out_size, void* d_ws, size_t ws_size,
                              hipStream_t stream)
{
  const float* x     = (const float*)d_in[0];
  const float* w_qkv = (const float*)d_in[1];
  const float* w_out = (const float*)d_in[2];
  const float* g1    = (const float*)d_in[3];
  const float* g2    = (const float*)d_in[4];
  const float* w1    = (const float*)d_in[5];
  const float* w3    = (const float*)d_in[6];
  const float* w2    = (const float*)d_in[7];
  float* outp = (float*)d_out;
  char* ws = (char*)d_ws;

  unsigned short* wT  = (unsigned short*)(ws);                 // 25,165,824
  unsigned short* y   = (unsigned short*)(ws + 25165824);      // 16,777,216
  unsigned short* qkv = (unsigned short*)(ws + 41943040);      // 50,331,648
  unsigned short* att = (unsigned short*)(ws + 92274688);      // 16,777,216
  float*          x1  = (float*)(ws + 109051904);              // 33,554,432
  unsigned short* s1  = (unsigned short*)(ws + 142606336);     // 46,137,344
  unsigned short* vTb = s1;                                    // vT (16.8MB), dead before s1
  unsigned short* h   = qkv;                                   // reuse after attn

  // x1 = x + attn(rmsnorm(x,g1)) @ w_out
  rmsnorm_bf16<<<4096, 256, 0, stream>>>(x, g1, y);
  transpose_w<<<dim3(192, 64), 256, 0, stream>>>(w_qkv, wT, 2048, 6144);
  gemm256<0><<<dim3(24, 16), 512, 0, stream>>>(y, wT, qkv, nullptr, nullptr, 4096, 6144, 2048);
  transpose_v<<<dim3(64, 4, 32), 256, 0, stream>>>(qkv, vTb);
  attn_fwd<<<dim3(16, 32), 256, 0, stream>>>(qkv, vTb, att);
  transpose_w<<<dim3(64, 64), 256, 0, stream>>>(w_out, wT, 2048, 2048);
  gemm_bt<3><<<dim3(16, 32), 256, 0, stream>>>(att, wT, x1, x, nullptr, 4096, 2048, 2048);

  // out = x1 + swiglu(rmsnorm(x1,g2))
  rmsnorm_bf16<<<4096, 256, 0, stream>>>(x1, g2, y);
  transpose_w<<<dim3(176, 64), 256, 0, stream>>>(w1, wT, 2048, 5632);
  gemm256<1><<<dim3(22, 16), 512, 0, stream>>>(y, wT, s1, nullptr, nullptr, 4096, 5632, 2048);
  transpose_w<<<dim3(176, 64), 256, 0, stream>>>(w3, wT, 2048, 5632);
  gemm256<2><<<dim3(22, 16), 512, 0, stream>>>(y, wT, h, nullptr, s1, 4096, 5632, 2048);
  transpose_w<<<dim3(64, 176), 256, 0, stream>>>(w2, wT, 5632, 2048);
  gemm_bt<3><<<dim3(16, 32), 256, 0, stream>>>(h, wT, outp, x1, nullptr, 4096, 2048, 5632);
}